// Round 1
// baseline (779.419 us; speedup 1.0000x reference)
//
#include <hip/hip_runtime.h>
#include <math.h>

#define DD   128
#define KX   65          // D/2+1
#define NB   4
#define NTT  2
#define NG   125
#define NBTG (NB*NTT*NG) // 1000
#define WIN  24
#define H0   52

__device__ __forceinline__ float2 cmul(float2 a, float2 b){
    return make_float2(a.x*b.x - a.y*b.y, a.x*b.y + a.y*b.x);
}

// tw[m] = e^{+2*pi*i*m/128}
__global__ void k_tw(float2* tw){
    int m = threadIdx.x;
    if (m < 128){
        double a = (2.0*M_PI/128.0)*(double)m;
        tw[m] = make_float2((float)cos(a), (float)sin(a));
    }
}

// Stage B: per z-slab: weight by sinc^2, rfft along x.  A1[z][y][kx]
__global__ __launch_bounds__(256) void k_volB(const float* __restrict__ vol,
                       const float2* __restrict__ twg, float2* __restrict__ A1){
    __shared__ float sV[DD*DD];
    __shared__ float2 sTw[128];
    int z = blockIdx.x, tid = threadIdx.x;
    if (tid < 128) sTw[tid] = twg[tid];
    float fz = (z-64)*(1.0f/128.0f);
    for (int i = tid; i < DD*DD; i += 256){
        int y = i >> 7, x = i & 127;
        float fy = (y-64)*(1.0f/128.0f);
        float fx = (x-64)*(1.0f/128.0f);
        float r = sqrtf(fz*fz + fy*fy + fx*fx);
        float s = (r > 0.f) ? (sinf((float)M_PI*r)/((float)M_PI*r)) : 1.0f;
        sV[i] = vol[(size_t)(z*DD + y)*DD + x] * s * s;
    }
    __syncthreads();
    for (int o = tid; o < DD*KX; o += 256){
        int y = o / KX, k = o - y*KX;
        float2 step = sTw[k]; step.y = -step.y;       // e^{-2pi i k/128}
        float2 cur = make_float2(1.f,0.f);
        float ar = 0.f, ai = 0.f;
        const float* row = &sV[y*DD];
        for (int x = 0; x < DD; ++x){
            if ((x & 15) == 0){ float2 t = sTw[(x*k)&127]; cur = make_float2(t.x, -t.y); }
            float v = row[x];
            ar += v*cur.x; ai += v*cur.y;
            cur = cmul(cur, step);
        }
        A1[(size_t)(z*DD + y)*KX + k] = make_float2(ar, ai);
    }
}

// Stage C: fft along y, in-place per z-slab.  A1[z][ky][kx]
__global__ __launch_bounds__(256) void k_volC(float2* __restrict__ A1,
                       const float2* __restrict__ twg){
    __shared__ float2 sS[DD*KX];
    __shared__ float2 sTw[128];
    int z = blockIdx.x, tid = threadIdx.x;
    if (tid < 128) sTw[tid] = twg[tid];
    for (int i = tid; i < DD*KX; i += 256) sS[i] = A1[(size_t)z*DD*KX + i];
    __syncthreads();
    for (int o = tid; o < DD*KX; o += 256){
        int ky = o / KX, k = o - ky*KX;
        float2 step = sTw[ky]; step.y = -step.y;
        float2 cur = make_float2(1.f,0.f);
        float ar=0.f, ai=0.f;
        for (int y = 0; y < DD; ++y){
            if ((y&15)==0){ float2 t = sTw[(y*ky)&127]; cur = make_float2(t.x, -t.y); }
            float2 v = sS[y*KX + k];
            ar += v.x*cur.x - v.y*cur.y;
            ai += v.x*cur.y + v.y*cur.x;
            cur = cmul(cur, step);
        }
        A1[(size_t)z*DD*KX + o] = make_float2(ar, ai);
    }
}

// Stage D: fft along z + (-1)^{kz+ky+kx} + fftshift store.  Vr[hz][hy][kx]
__global__ __launch_bounds__(256) void k_volD(const float2* __restrict__ A1,
                       const float2* __restrict__ twg, float2* __restrict__ Vr){
    __shared__ float2 sS[DD*KX];
    __shared__ float2 sTw[128];
    int ky = blockIdx.x, tid = threadIdx.x;
    if (tid < 128) sTw[tid] = twg[tid];
    for (int i = tid; i < DD*KX; i += 256){
        int z = i / KX, k = i - z*KX;
        sS[i] = A1[((size_t)z*DD + ky)*KX + k];
    }
    __syncthreads();
    int hy = (ky + 64) & 127;
    for (int o = tid; o < DD*KX; o += 256){
        int hz = o / KX, k = o - hz*KX;
        int kz = (hz + 64) & 127;
        float2 step = sTw[kz]; step.y = -step.y;
        float2 cur = make_float2(1.f,0.f);
        float ar=0.f, ai=0.f;
        for (int zz = 0; zz < DD; ++zz){
            if ((zz&15)==0){ float2 t = sTw[(zz*kz)&127]; cur = make_float2(t.x,-t.y); }
            float2 v = sS[zz*KX + k];
            ar += v.x*cur.x - v.y*cur.y;
            ai += v.x*cur.y + v.y*cur.x;
            cur = cmul(cur, step);
        }
        float sgn = ((hz + hy + k) & 1) ? -1.f : 1.f;
        Vr[((size_t)hz*DD + hy)*KX + k] = make_float2(ar*sgn, ai*sgn);
    }
}

// Image rfft along x.  B1[b][y][kx]
__global__ __launch_bounds__(256) void k_fimgB(const float* __restrict__ imgs,
                        const float2* __restrict__ twg, float2* __restrict__ B1){
    __shared__ float2 sTw[128];
    if (threadIdx.x < 128) sTw[threadIdx.x] = twg[threadIdx.x];
    __syncthreads();
    int o = blockIdx.x*256 + threadIdx.x;
    if (o >= NB*DD*KX) return;
    int b = o / (DD*KX);
    int r = o - b*DD*KX;
    int y = r / KX, k = r - y*KX;
    const float* row = imgs + (size_t)(b*DD + y)*DD;
    float2 step = sTw[k]; step.y = -step.y;
    float2 cur = make_float2(1.f,0.f);
    float ar=0.f, ai=0.f;
    for (int x=0;x<DD;++x){
        if ((x&15)==0){ float2 t = sTw[(x*k)&127]; cur = make_float2(t.x,-t.y); }
        float v = row[x];
        ar += v*cur.x; ai += v*cur.y;
        cur = cmul(cur, step);
    }
    B1[o] = make_float2(ar, ai);
}

// Image fft along y + signs + y-shift.  Fimg[b][h][kx]
__global__ __launch_bounds__(256) void k_fimgY(const float2* __restrict__ B1,
                        const float2* __restrict__ twg, float2* __restrict__ Fimg){
    __shared__ float2 sTw[128];
    if (threadIdx.x < 128) sTw[threadIdx.x] = twg[threadIdx.x];
    __syncthreads();
    int o = blockIdx.x*256 + threadIdx.x;
    if (o >= NB*DD*KX) return;
    int b = o / (DD*KX);
    int r = o - b*DD*KX;
    int h = r / KX, k = r - h*KX;
    int kky = (h + 64) & 127;
    float2 step = sTw[kky]; step.y = -step.y;
    float2 cur = make_float2(1.f,0.f);
    float ar=0.f, ai=0.f;
    const float2* col = B1 + (size_t)b*DD*KX + k;
    for (int y=0;y<DD;++y){
        if ((y&15)==0){ float2 t = sTw[(y*kky)&127]; cur = make_float2(t.x,-t.y); }
        float2 v = col[(size_t)y*KX];
        ar += v.x*cur.x - v.y*cur.y;
        ai += v.x*cur.y + v.y*cur.x;
        cur = cmul(cur, step);
    }
    float sgn = ((h + k)&1) ? -1.f : 1.f;
    Fimg[o] = make_float2(ar*sgn, ai*sgn);
}

// Main: per (b,t,g): slice-extract -> prod -> partial 2D inverse rFFT on the
// 24x24 window -> argmax (row-major first occurrence).
__global__ __launch_bounds__(256) void k_main(
    const float2* __restrict__ Vr, const float2* __restrict__ Fimg,
    const float* __restrict__ ctf, const float* __restrict__ rotm,
    const float* __restrict__ grid, const float2* __restrict__ twg,
    float* __restrict__ resVal, int2* __restrict__ resShift)
{
    __shared__ float2 sProd[DD*KX];   // 66560 B
    __shared__ float2 sT[WIN*KX];     // 12480 B
    __shared__ float2 sTw[128];       // 1024 B
    __shared__ float  sM[9];

    int tid = threadIdx.x;
    int blk = blockIdx.x;
    int b  = blk / (NTT*NG);
    int rr = blk - b*NTT*NG;
    int t  = rr / NG;
    int g  = rr - t*NG;

    if (tid < 128) sTw[tid] = twg[tid];
    if (tid < 9){
        int i = tid/3, k = tid - 3*i;
        const float* R  = rotm + (size_t)(b*NTT + t)*9;
        const float* Gm = grid + (size_t)g*9;
        sM[tid] = R[i*3+0]*Gm[0*3+k] + R[i*3+1]*Gm[1*3+k] + R[i*3+2]*Gm[2*3+k];
    }
    __syncthreads();

    float M00=sM[0], M01=sM[1], M10=sM[3], M11=sM[4], M20=sM[6], M21=sM[7];

    // Phase 1: central slice (trilinear, conj-flip) * ctf, conj, * fimg
    for (int idx = tid; idx < DD*KX; idx += 256){
        int h = idx / KX, w = idx - h*KX;
        float fy = (h - 64)*(1.0f/128.0f);
        float fx = w*(1.0f/128.0f);
        float rz = M21*fy + M20*fx;
        float ry = M11*fy + M10*fx;
        float rx = M01*fy + M00*fx;
        bool neg = rx < 0.f;
        if (neg){ rz=-rz; ry=-ry; rx=-rx; }
        float zi = rz*128.f + 64.f;
        float yi = ry*128.f + 64.f;
        float xi = rx*128.f;
        float z0f = floorf(zi), y0f = floorf(yi), x0f = floorf(xi);
        float fz2 = zi - z0f, fy2 = yi - y0f, fx2 = xi - x0f;
        int z0 = (int)z0f, y0 = (int)y0f, x0 = (int)x0f;
        float sr = 0.f, si = 0.f;
        #pragma unroll
        for (int dz = 0; dz < 2; ++dz){
            int zc = z0 + dz;
            if (zc < 0 || zc >= DD) continue;
            float wz = dz ? fz2 : 1.f - fz2;
            #pragma unroll
            for (int dy = 0; dy < 2; ++dy){
                int yc = y0 + dy;
                if (yc < 0 || yc >= DD) continue;
                float wy = dy ? fy2 : 1.f - fy2;
                #pragma unroll
                for (int dx = 0; dx < 2; ++dx){
                    int xc = x0 + dx;
                    if (xc < 0 || xc >= KX) continue;
                    float wx = dx ? fx2 : 1.f - fx2;
                    float wgt = wz*wy*wx;
                    float2 v = Vr[((size_t)zc*DD + yc)*KX + xc];
                    sr += v.x*wgt; si += v.y*wgt;
                }
            }
        }
        if (neg) si = -si;
        float cf = ctf[(size_t)(b*DD + h)*KX + w];
        float pr = sr*cf, pi = si*cf;
        float2 f = Fimg[(size_t)(b*DD + h)*KX + w];
        // fimg * conj(proj)
        sProd[idx] = make_float2(f.x*pr + f.y*pi, f.y*pr - f.x*pi);
    }
    __syncthreads();

    // Phase 2: partial inverse DFT along y (24 needed rows)
    for (int o = tid; o < WIN*KX; o += 256){
        int a = o / KX, k = o - a*KX;
        int ry = (116 + a) & 127;
        float2 step = sTw[ry];                 // e^{+2pi i ry/128}
        float2 cur = make_float2(1.f,0.f);
        float ar=0.f, ai=0.f;
        for (int h = 0; h < DD; ++h){
            if ((h&15)==0) cur = sTw[(h*ry)&127];
            float2 p = sProd[h*KX + k];
            ar += p.x*cur.x - p.y*cur.y;
            ai += p.x*cur.y + p.y*cur.x;
            cur = cmul(cur, step);
        }
        float sgn = (a & 1) ? -1.f : 1.f;      // (-1)^{ry}; ry parity == a parity
        sT[o] = make_float2(ar*sgn*(1.f/128.f), ai*sgn*(1.f/128.f));
    }
    __syncthreads();

    // Phase 3: partial irfft along x (24 needed cols)
    float* sC = reinterpret_cast<float*>(sProd);
    for (int o = tid; o < WIN*WIN; o += 256){
        int a = o / WIN, bx = o - a*WIN;
        int rx = (116 + bx) & 127;
        const float2* Trow = &sT[a*KX];
        float acc = Trow[0].x + ((bx & 1) ? -Trow[64].x : Trow[64].x);
        for (int k = 1; k < 64; ++k){
            float2 e = sTw[(k*rx)&127];
            acc += 2.f*(Trow[k].x*e.x - Trow[k].y*e.y);
        }
        sC[o] = acc*(1.f/128.f);
    }
    __syncthreads();

    // Phase 4: argmax, row-major first occurrence tie-break
    float best = -3.402823466e38f; int bidx = 0;
    for (int i = tid; i < WIN*WIN; i += 256){
        float v = sC[i];
        if (v > best){ best = v; bidx = i; }
    }
    float* sRv = sC + WIN*WIN;
    int*   sRi = reinterpret_cast<int*>(sRv + 256);
    sRv[tid] = best; sRi[tid] = bidx;
    __syncthreads();
    for (int s = 128; s > 0; s >>= 1){
        if (tid < s){
            float v2 = sRv[tid+s]; int i2 = sRi[tid+s];
            float v1 = sRv[tid];   int i1 = sRi[tid];
            if (v2 > v1 || (v2 == v1 && i2 < i1)){ sRv[tid] = v2; sRi[tid] = i2; }
        }
        __syncthreads();
    }
    if (tid == 0){
        int i = sRi[0];
        int a = i / WIN, bx = i - a*WIN;
        resVal[blk] = sRv[0];
        resShift[blk] = make_int2(H0 + bx, H0 + a);
    }
}

// Final: per-batch top-2 (stable ties), mean/std(ddof=1), erf, outputs.
__global__ void k_final(const float* __restrict__ resVal, const int2* __restrict__ resShift,
                        const float* __restrict__ grid, float* __restrict__ out)
{
    int b = blockIdx.x;
    if (threadIdx.x != 0) return;
    const int N = NTT*NG;   // 250
    const float* v = resVal + (size_t)b*N;
    int i0 = 0; float v0 = v[0];
    for (int i = 1; i < N; ++i){ float x = v[i]; if (x > v0){ v0 = x; i0 = i; } }
    int i1 = 0; float v1 = -3.402823466e38f;
    for (int i = 0; i < N; ++i){ if (i == i0) continue; float x = v[i]; if (x > v1){ v1 = x; i1 = i; } }
    float sum = 0.f;
    for (int i = 0; i < N; ++i) sum += v[i];
    float mean = sum / (float)N;
    float ss = 0.f;
    for (int i = 0; i < N; ++i){ float d = v[i] - mean; ss += d*d; }
    float stdv = sqrtf(ss / (float)(N - 1));
    float vals[2] = {v0, v1};
    int   idxs[2] = {i0, i1};
    for (int k = 0; k < 2; ++k){
        out[b*2 + k] = vals[k];
        int gi = idxs[k] % NG;
        for (int j = 0; j < 9; ++j) out[8 + (b*2+k)*9 + j] = grid[(size_t)gi*9 + j];
        int2 sh = resShift[(size_t)b*N + idxs[k]];
        out[80 + (b*2+k)*2 + 0] = -((float)sh.x - 64.f)*1.5f;
        out[80 + (b*2+k)*2 + 1] = -((float)sh.y - 64.f)*1.5f;
        out[96 + b*2 + k] = 0.5f*(1.f + erff((vals[k] - mean)/(stdv*1.41421356237309515f)));
    }
}

extern "C" void kernel_launch(void* const* d_in, const int* in_sizes, int n_in,
                              void* d_out, int out_size, void* d_ws, size_t ws_size,
                              hipStream_t stream)
{
    const float* vol  = (const float*)d_in[0];
    const float* imgs = (const float*)d_in[1];
    const float* ctf  = (const float*)d_in[2];
    const float* rotm = (const float*)d_in[3];
    const float* grid = (const float*)d_in[4];
    float* out = (float*)d_out;

    char* ws = (char*)d_ws;
    size_t off = 0;
    float2* tw = (float2*)(ws + off); off += 1024;
    float2* A1 = (float2*)(ws + off); off += (size_t)DD*DD*KX*sizeof(float2);
    float2* Vr = (float2*)(ws + off); off += (size_t)DD*DD*KX*sizeof(float2);
    float2* B1 = (float2*)(ws + off); off += (size_t)NB*DD*KX*sizeof(float2);
    float2* Fi = (float2*)(ws + off); off += (size_t)NB*DD*KX*sizeof(float2);
    float* resVal = (float*)(ws + off); off += (size_t)NBTG*sizeof(float);
    int2* resShift = (int2*)(ws + off); off += (size_t)NBTG*sizeof(int2);

    k_tw   <<<1,   128, 0, stream>>>(tw);
    k_volB <<<DD,  256, 0, stream>>>(vol, tw, A1);
    k_volC <<<DD,  256, 0, stream>>>(A1, tw);
    k_volD <<<DD,  256, 0, stream>>>(A1, tw, Vr);
    k_fimgB<<<130, 256, 0, stream>>>(imgs, tw, B1);
    k_fimgY<<<130, 256, 0, stream>>>(B1, tw, Fi);
    k_main <<<NBTG,256, 0, stream>>>(Vr, Fi, ctf, rotm, grid, tw, resVal, resShift);
    k_final<<<NB,  64,  0, stream>>>(resVal, resShift, grid, out);
}

// Round 2
// 319.177 us; speedup vs baseline: 2.4420x; 2.4420x over previous
//
#include <hip/hip_runtime.h>
#include <math.h>
#include <float.h>

#define DD   128
#define KX   65          // D/2+1
#define NB   4
#define NTT  2
#define NG   125
#define NBTG (NB*NTT*NG) // 1000
#define WIN  24
#define H0   52

__device__ __forceinline__ float2 cmul(float2 a, float2 b){
    return make_float2(a.x*b.x - a.y*b.y, a.x*b.y + a.y*b.x);
}

// tw[m] = e^{+2*pi*i*m/128}
__global__ void k_tw(float2* tw){
    int m = threadIdx.x;
    if (m < 128){
        double a = (2.0*M_PI/128.0)*(double)m;
        tw[m] = make_float2((float)cos(a), (float)sin(a));
    }
}

// Stage B: rfft along x with sinc^2 weight. grid 512: (z, quarter-of-y)
__global__ __launch_bounds__(256) void k_volB(const float* __restrict__ vol,
                       const float2* __restrict__ twg, float2* __restrict__ A1){
    __shared__ float sV[32*DD];
    __shared__ float2 sTw[128];
    int bid = blockIdx.x;
    int z = bid >> 2, q = bid & 3;
    int y0 = q*32;
    int tid = threadIdx.x;
    if (tid < 128) sTw[tid] = twg[tid];
    float fz = (z-64)*(1.0f/128.0f);
    for (int i = tid; i < 32*DD; i += 256){
        int y = y0 + (i >> 7), x = i & 127;
        float fy = (y-64)*(1.0f/128.0f);
        float fx = (x-64)*(1.0f/128.0f);
        float r = sqrtf(fz*fz + fy*fy + fx*fx);
        float s = (r > 0.f) ? (sinf((float)M_PI*r)/((float)M_PI*r)) : 1.0f;
        sV[i] = vol[(size_t)(z*DD + y)*DD + x] * s * s;
    }
    __syncthreads();
    for (int o = tid; o < 32*KX; o += 256){
        int yy = o / KX, k = o - yy*KX;
        const float* row = &sV[yy*DD];
        float ar0=0,ai0=0,ar1=0,ai1=0,ar2=0,ai2=0,ar3=0,ai3=0;
        int i0=0, i1=k&127, i2=(2*k)&127, i3=(3*k)&127;
        int st = (4*k)&127;
        for (int x = 0; x < DD; x += 4){
            float4 v4 = *reinterpret_cast<const float4*>(&row[x]);
            float2 e0=sTw[i0], e1=sTw[i1], e2=sTw[i2], e3=sTw[i3];
            ar0 += v4.x*e0.x; ai0 -= v4.x*e0.y;
            ar1 += v4.y*e1.x; ai1 -= v4.y*e1.y;
            ar2 += v4.z*e2.x; ai2 -= v4.z*e2.y;
            ar3 += v4.w*e3.x; ai3 -= v4.w*e3.y;
            i0=(i0+st)&127; i1=(i1+st)&127; i2=(i2+st)&127; i3=(i3+st)&127;
        }
        A1[((size_t)z*DD + y0+yy)*KX + k] = make_float2(ar0+ar1+ar2+ar3, ai0+ai1+ai2+ai3);
    }
}

// Stage C: fft along y. grid 512: (z, quarter-of-outputs).
__global__ __launch_bounds__(256) void k_volC(const float2* __restrict__ A1in,
                       float2* __restrict__ A1out, const float2* __restrict__ twg){
    __shared__ float2 sS[DD*KX];
    __shared__ float2 sTw[128];
    int bid = blockIdx.x;
    int z = bid >> 2, q = bid & 3;
    int tid = threadIdx.x;
    if (tid < 128) sTw[tid] = twg[tid];
    for (int i = tid; i < DD*KX; i += 256) sS[i] = A1in[(size_t)z*DD*KX + i];
    __syncthreads();
    for (int oo = tid; oo < 32*KX; oo += 256){
        int o = q*32*KX + oo;
        int ky = o / KX, k = o - ky*KX;
        const float2* col = &sS[k];
        float ar0=0,ai0=0,ar1=0,ai1=0,ar2=0,ai2=0,ar3=0,ai3=0;
        int i0=0, i1=ky&127, i2=(2*ky)&127, i3=(3*ky)&127;
        int st = (4*ky)&127;
        for (int y = 0; y < DD; y += 4){
            float2 v0=col[(y+0)*KX], v1=col[(y+1)*KX], v2=col[(y+2)*KX], v3=col[(y+3)*KX];
            float2 e0=sTw[i0], e1=sTw[i1], e2=sTw[i2], e3=sTw[i3];
            ar0 += v0.x*e0.x + v0.y*e0.y;  ai0 += v0.y*e0.x - v0.x*e0.y;
            ar1 += v1.x*e1.x + v1.y*e1.y;  ai1 += v1.y*e1.x - v1.x*e1.y;
            ar2 += v2.x*e2.x + v2.y*e2.y;  ai2 += v2.y*e2.x - v2.x*e2.y;
            ar3 += v3.x*e3.x + v3.y*e3.y;  ai3 += v3.y*e3.x - v3.x*e3.y;
            i0=(i0+st)&127; i1=(i1+st)&127; i2=(i2+st)&127; i3=(i3+st)&127;
        }
        A1out[(size_t)z*DD*KX + o] = make_float2(ar0+ar1+ar2+ar3, ai0+ai1+ai2+ai3);
    }
}

// Stage D: fft along z + (-1)^{kz+ky+kx} + fftshift store. grid 512: (ky, quarter)
__global__ __launch_bounds__(256) void k_volD(const float2* __restrict__ A1,
                       const float2* __restrict__ twg, float2* __restrict__ Vr){
    __shared__ float2 sS[DD*KX];
    __shared__ float2 sTw[128];
    int bid = blockIdx.x;
    int ky = bid >> 2, q = bid & 3;
    int tid = threadIdx.x;
    if (tid < 128) sTw[tid] = twg[tid];
    for (int i = tid; i < DD*KX; i += 256){
        int z = i / KX, k = i - z*KX;
        sS[i] = A1[((size_t)z*DD + ky)*KX + k];
    }
    __syncthreads();
    int hy = (ky + 64) & 127;
    for (int oo = tid; oo < 32*KX; oo += 256){
        int lhz = oo / KX;
        int k   = oo - lhz*KX;
        int hz  = q*32 + lhz;
        int kz  = (hz + 64) & 127;
        const float2* col = &sS[k];
        float ar0=0,ai0=0,ar1=0,ai1=0,ar2=0,ai2=0,ar3=0,ai3=0;
        int i0=0, i1=kz&127, i2=(2*kz)&127, i3=(3*kz)&127;
        int st = (4*kz)&127;
        for (int zz = 0; zz < DD; zz += 4){
            float2 v0=col[(zz+0)*KX], v1=col[(zz+1)*KX], v2=col[(zz+2)*KX], v3=col[(zz+3)*KX];
            float2 e0=sTw[i0], e1=sTw[i1], e2=sTw[i2], e3=sTw[i3];
            ar0 += v0.x*e0.x + v0.y*e0.y;  ai0 += v0.y*e0.x - v0.x*e0.y;
            ar1 += v1.x*e1.x + v1.y*e1.y;  ai1 += v1.y*e1.x - v1.x*e1.y;
            ar2 += v2.x*e2.x + v2.y*e2.y;  ai2 += v2.y*e2.x - v2.x*e2.y;
            ar3 += v3.x*e3.x + v3.y*e3.y;  ai3 += v3.y*e3.x - v3.x*e3.y;
            i0=(i0+st)&127; i1=(i1+st)&127; i2=(i2+st)&127; i3=(i3+st)&127;
        }
        float sgn = ((hz + hy + k) & 1) ? -1.f : 1.f;
        Vr[((size_t)hz*DD + hy)*KX + k] =
            make_float2((ar0+ar1+ar2+ar3)*sgn, (ai0+ai1+ai2+ai3)*sgn);
    }
}

// Image rfft along x.  B1[b][y][kx]
__global__ __launch_bounds__(256) void k_fimgB(const float* __restrict__ imgs,
                        const float2* __restrict__ twg, float2* __restrict__ B1){
    __shared__ float2 sTw[128];
    if (threadIdx.x < 128) sTw[threadIdx.x] = twg[threadIdx.x];
    __syncthreads();
    int o = blockIdx.x*256 + threadIdx.x;
    if (o >= NB*DD*KX) return;
    int b = o / (DD*KX);
    int r = o - b*DD*KX;
    int y = r / KX, k = r - y*KX;
    const float* row = imgs + (size_t)(b*DD + y)*DD;
    float ar0=0,ai0=0,ar1=0,ai1=0,ar2=0,ai2=0,ar3=0,ai3=0;
    int i0=0, i1=k&127, i2=(2*k)&127, i3=(3*k)&127;
    int st = (4*k)&127;
    for (int x = 0; x < DD; x += 4){
        float v0=row[x], v1=row[x+1], v2=row[x+2], v3=row[x+3];
        float2 e0=sTw[i0], e1=sTw[i1], e2=sTw[i2], e3=sTw[i3];
        ar0 += v0*e0.x; ai0 -= v0*e0.y;
        ar1 += v1*e1.x; ai1 -= v1*e1.y;
        ar2 += v2*e2.x; ai2 -= v2*e2.y;
        ar3 += v3*e3.x; ai3 -= v3*e3.y;
        i0=(i0+st)&127; i1=(i1+st)&127; i2=(i2+st)&127; i3=(i3+st)&127;
    }
    B1[o] = make_float2(ar0+ar1+ar2+ar3, ai0+ai1+ai2+ai3);
}

// Image fft along y + signs + y-shift.  Fimg[b][h][kx]
__global__ __launch_bounds__(256) void k_fimgY(const float2* __restrict__ B1,
                        const float2* __restrict__ twg, float2* __restrict__ Fimg){
    __shared__ float2 sTw[128];
    if (threadIdx.x < 128) sTw[threadIdx.x] = twg[threadIdx.x];
    __syncthreads();
    int o = blockIdx.x*256 + threadIdx.x;
    if (o >= NB*DD*KX) return;
    int b = o / (DD*KX);
    int r = o - b*DD*KX;
    int h = r / KX, k = r - h*KX;
    int kky = (h + 64) & 127;
    const float2* col = B1 + (size_t)b*DD*KX + k;
    float ar0=0,ai0=0,ar1=0,ai1=0,ar2=0,ai2=0,ar3=0,ai3=0;
    int i0=0, i1=kky&127, i2=(2*kky)&127, i3=(3*kky)&127;
    int st = (4*kky)&127;
    for (int y = 0; y < DD; y += 4){
        float2 v0=col[(size_t)(y+0)*KX], v1=col[(size_t)(y+1)*KX];
        float2 v2=col[(size_t)(y+2)*KX], v3=col[(size_t)(y+3)*KX];
        float2 e0=sTw[i0], e1=sTw[i1], e2=sTw[i2], e3=sTw[i3];
        ar0 += v0.x*e0.x + v0.y*e0.y;  ai0 += v0.y*e0.x - v0.x*e0.y;
        ar1 += v1.x*e1.x + v1.y*e1.y;  ai1 += v1.y*e1.x - v1.x*e1.y;
        ar2 += v2.x*e2.x + v2.y*e2.y;  ai2 += v2.y*e2.x - v2.x*e2.y;
        ar3 += v3.x*e3.x + v3.y*e3.y;  ai3 += v3.y*e3.x - v3.x*e3.y;
        i0=(i0+st)&127; i1=(i1+st)&127; i2=(i2+st)&127; i3=(i3+st)&127;
    }
    float sgn = ((h + k)&1) ? -1.f : 1.f;
    Fimg[o] = make_float2((ar0+ar1+ar2+ar3)*sgn, (ai0+ai1+ai2+ai3)*sgn);
}

// Main: per (b,t,g): slice-extract -> prod -> partial 2D inverse rFFT on the
// 24x24 window -> argmax (row-major first occurrence).
__global__ __launch_bounds__(256) void k_main(
    const float2* __restrict__ Vr, const float2* __restrict__ Fimg,
    const float* __restrict__ ctf, const float* __restrict__ rotm,
    const float* __restrict__ grid, const float2* __restrict__ twg,
    float* __restrict__ resVal, int2* __restrict__ resShift)
{
    __shared__ float2 sProd[DD*KX];   // 66560 B
    __shared__ float2 sT[WIN*KX];     // 12480 B
    __shared__ float2 sTw[128];       // 1024 B
    __shared__ float  sM[9];

    int tid = threadIdx.x;
    int blk = blockIdx.x;
    int b  = blk / (NTT*NG);
    int rr = blk - b*NTT*NG;
    int t  = rr / NG;
    int g  = rr - t*NG;

    if (tid < 128) sTw[tid] = twg[tid];
    if (tid < 9){
        int i = tid/3, k = tid - 3*i;
        const float* R  = rotm + (size_t)(b*NTT + t)*9;
        const float* Gm = grid + (size_t)g*9;
        sM[tid] = R[i*3+0]*Gm[0*3+k] + R[i*3+1]*Gm[1*3+k] + R[i*3+2]*Gm[2*3+k];
    }
    __syncthreads();

    float M00=sM[0], M01=sM[1], M10=sM[3], M11=sM[4], M20=sM[6], M21=sM[7];

    // Phase 1: central slice (trilinear, conj-flip) * ctf, conj, * fimg
    for (int idx = tid; idx < DD*KX; idx += 256){
        int h = idx / KX, w = idx - h*KX;
        float fy = (h - 64)*(1.0f/128.0f);
        float fx = w*(1.0f/128.0f);
        float rz = M21*fy + M20*fx;
        float ry = M11*fy + M10*fx;
        float rx = M01*fy + M00*fx;
        bool neg = rx < 0.f;
        if (neg){ rz=-rz; ry=-ry; rx=-rx; }
        float zi = rz*128.f + 64.f;
        float yi = ry*128.f + 64.f;
        float xi = rx*128.f;
        float z0f = floorf(zi), y0f = floorf(yi), x0f = floorf(xi);
        float fz2 = zi - z0f, fy2 = yi - y0f, fx2 = xi - x0f;
        int z0 = (int)z0f, y0 = (int)y0f, x0 = (int)x0f;
        float sr = 0.f, si = 0.f;
        #pragma unroll
        for (int c = 0; c < 8; ++c){
            int dz = c>>2, dy = (c>>1)&1, dx = c&1;
            int zc = z0+dz, yc = y0+dy, xc = x0+dx;
            float wgt = (dz?fz2:1.f-fz2)*(dy?fy2:1.f-fy2)*(dx?fx2:1.f-fx2);
            bool ok = (zc>=0) & (zc<DD) & (yc>=0) & (yc<DD) & (xc>=0) & (xc<KX);
            wgt = ok ? wgt : 0.f;
            int zcc = min(max(zc,0),DD-1), ycc = min(max(yc,0),DD-1), xcc = min(max(xc,0),KX-1);
            float2 v = Vr[((size_t)zcc*DD + ycc)*KX + xcc];
            sr += v.x*wgt; si += v.y*wgt;
        }
        if (neg) si = -si;
        float cf = ctf[(size_t)(b*DD + h)*KX + w];
        float pr = sr*cf, pi = si*cf;
        float2 f = Fimg[(size_t)(b*DD + h)*KX + w];
        // fimg * conj(proj)
        sProd[idx] = make_float2(f.x*pr + f.y*pi, f.y*pr - f.x*pi);
    }
    __syncthreads();

    // Phase 2: partial inverse DFT along y (24 needed rows)
    for (int o = tid; o < WIN*KX; o += 256){
        int a = o / KX, k = o - a*KX;
        int ry = (116 + a) & 127;
        const float2* p = &sProd[k];
        float ar0=0,ai0=0,ar1=0,ai1=0,ar2=0,ai2=0,ar3=0,ai3=0;
        int i0=0, i1=ry, i2=(2*ry)&127, i3=(3*ry)&127;
        int st = (4*ry)&127;
        #pragma unroll 2
        for (int h = 0; h < DD; h += 4){
            float2 p0=p[(h+0)*KX], p1=p[(h+1)*KX], p2=p[(h+2)*KX], p3=p[(h+3)*KX];
            float2 e0=sTw[i0], e1=sTw[i1], e2=sTw[i2], e3=sTw[i3];
            ar0 += p0.x*e0.x - p0.y*e0.y;  ai0 += p0.x*e0.y + p0.y*e0.x;
            ar1 += p1.x*e1.x - p1.y*e1.y;  ai1 += p1.x*e1.y + p1.y*e1.x;
            ar2 += p2.x*e2.x - p2.y*e2.y;  ai2 += p2.x*e2.y + p2.y*e2.x;
            ar3 += p3.x*e3.x - p3.y*e3.y;  ai3 += p3.x*e3.y + p3.y*e3.x;
            i0=(i0+st)&127; i1=(i1+st)&127; i2=(i2+st)&127; i3=(i3+st)&127;
        }
        float sgn = (a & 1) ? -(1.f/128.f) : (1.f/128.f);
        sT[o] = make_float2((ar0+ar1+ar2+ar3)*sgn, (ai0+ai1+ai2+ai3)*sgn);
    }
    __syncthreads();

    // Phase 3: partial irfft along x (24 needed cols)
    float* sC = reinterpret_cast<float*>(sProd);
    for (int o = tid; o < WIN*WIN; o += 256){
        int a = o / WIN, bx = o - a*WIN;
        int rx = (116 + bx) & 127;
        const float2* Trow = &sT[a*KX];
        float acc0 = Trow[0].x + ((bx & 1) ? -Trow[64].x : Trow[64].x);
        float acc1 = 0.f;
        int j1 = rx, j2 = (2*rx)&127;
        int st = (2*rx)&127;
        for (int k = 1; k < 63; k += 2){
            float2 e1 = sTw[j1]; float2 T1 = Trow[k];
            float2 e2 = sTw[j2]; float2 T2 = Trow[k+1];
            acc0 += 2.f*(T1.x*e1.x - T1.y*e1.y);
            acc1 += 2.f*(T2.x*e2.x - T2.y*e2.y);
            j1=(j1+st)&127; j2=(j2+st)&127;
        }
        {
            float2 e = sTw[(63*rx)&127]; float2 T = Trow[63];
            acc0 += 2.f*(T.x*e.x - T.y*e.y);
        }
        sC[o] = (acc0+acc1)*(1.f/128.f);
    }
    __syncthreads();

    // Phase 4: argmax, row-major first occurrence tie-break
    float best = -FLT_MAX; int bidx = 0;
    for (int i = tid; i < WIN*WIN; i += 256){
        float v = sC[i];
        if (v > best){ best = v; bidx = i; }
    }
    float* sRv = sC + WIN*WIN;
    int*   sRi = reinterpret_cast<int*>(sRv + 256);
    sRv[tid] = best; sRi[tid] = bidx;
    __syncthreads();
    for (int s = 128; s > 0; s >>= 1){
        if (tid < s){
            float v2 = sRv[tid+s]; int i2 = sRi[tid+s];
            float v1 = sRv[tid];   int i1 = sRi[tid];
            if (v2 > v1 || (v2 == v1 && i2 < i1)){ sRv[tid] = v2; sRi[tid] = i2; }
        }
        __syncthreads();
    }
    if (tid == 0){
        int i = sRi[0];
        int a = i / WIN, bx = i - a*WIN;
        resVal[blk] = sRv[0];
        resShift[blk] = make_int2(H0 + bx, H0 + a);
    }
}

// Final: per-batch top-2 (stable ties), mean/std(ddof=1), erf — parallel.
__global__ __launch_bounds__(256) void k_final(const float* __restrict__ resVal,
                        const int2* __restrict__ resShift,
                        const float* __restrict__ grid, float* __restrict__ out)
{
    __shared__ float sv[256];
    __shared__ int   si[256];
    __shared__ float sr[256];
    __shared__ float sMean;
    const int N = NTT*NG;   // 250
    int b = blockIdx.x, tid = threadIdx.x;
    const float* v = resVal + (size_t)b*N;
    float myv = (tid < N) ? v[tid] : -FLT_MAX;

    sv[tid] = myv; si[tid] = (tid < N) ? tid : 0x7fffffff;
    __syncthreads();
    for (int s = 128; s > 0; s >>= 1){
        if (tid < s){
            float v2 = sv[tid+s]; int i2 = si[tid+s];
            if (v2 > sv[tid] || (v2 == sv[tid] && i2 < si[tid])){ sv[tid]=v2; si[tid]=i2; }
        }
        __syncthreads();
    }
    float v0 = sv[0]; int i0 = si[0];
    __syncthreads();

    bool act = (tid < N) && (tid != i0);
    sv[tid] = act ? myv : -FLT_MAX; si[tid] = act ? tid : 0x7fffffff;
    __syncthreads();
    for (int s = 128; s > 0; s >>= 1){
        if (tid < s){
            float v2 = sv[tid+s]; int i2 = si[tid+s];
            if (v2 > sv[tid] || (v2 == sv[tid] && i2 < si[tid])){ sv[tid]=v2; si[tid]=i2; }
        }
        __syncthreads();
    }
    float v1 = sv[0]; int i1 = si[0];
    __syncthreads();

    sr[tid] = (tid < N) ? myv : 0.f;
    __syncthreads();
    for (int s = 128; s > 0; s >>= 1){
        if (tid < s) sr[tid] += sr[tid+s];
        __syncthreads();
    }
    if (tid == 0) sMean = sr[0] / (float)N;
    __syncthreads();
    float mean = sMean;

    float d = (tid < N) ? (myv - mean) : 0.f;
    sr[tid] = d*d;
    __syncthreads();
    for (int s = 128; s > 0; s >>= 1){
        if (tid < s) sr[tid] += sr[tid+s];
        __syncthreads();
    }

    if (tid == 0){
        float stdv = sqrtf(sr[0] / (float)(N - 1));
        float vals[2] = {v0, v1};
        int   idxs[2] = {i0, i1};
        for (int k = 0; k < 2; ++k){
            out[b*2 + k] = vals[k];
            int gi = idxs[k] % NG;
            for (int j = 0; j < 9; ++j) out[8 + (b*2+k)*9 + j] = grid[(size_t)gi*9 + j];
            int2 sh = resShift[(size_t)b*N + idxs[k]];
            out[80 + (b*2+k)*2 + 0] = -((float)sh.x - 64.f)*1.5f;
            out[80 + (b*2+k)*2 + 1] = -((float)sh.y - 64.f)*1.5f;
            out[96 + b*2 + k] = 0.5f*(1.f + erff((vals[k] - mean)/(stdv*1.41421356237309515f)));
        }
    }
}

extern "C" void kernel_launch(void* const* d_in, const int* in_sizes, int n_in,
                              void* d_out, int out_size, void* d_ws, size_t ws_size,
                              hipStream_t stream)
{
    const float* vol  = (const float*)d_in[0];
    const float* imgs = (const float*)d_in[1];
    const float* ctf  = (const float*)d_in[2];
    const float* rotm = (const float*)d_in[3];
    const float* grid = (const float*)d_in[4];
    float* out = (float*)d_out;

    char* ws = (char*)d_ws;
    size_t off = 0;
    float2* tw = (float2*)(ws + off); off += 1024;
    float2* A1 = (float2*)(ws + off); off += (size_t)DD*DD*KX*sizeof(float2);
    float2* A2 = (float2*)(ws + off); off += (size_t)DD*DD*KX*sizeof(float2);
    float2* Vr = (float2*)(ws + off); off += (size_t)DD*DD*KX*sizeof(float2);
    float2* B1 = (float2*)(ws + off); off += (size_t)NB*DD*KX*sizeof(float2);
    float2* Fi = (float2*)(ws + off); off += (size_t)NB*DD*KX*sizeof(float2);
    float* resVal = (float*)(ws + off); off += (size_t)NBTG*sizeof(float);
    int2* resShift = (int2*)(ws + off); off += (size_t)NBTG*sizeof(int2);

    k_tw   <<<1,   128, 0, stream>>>(tw);
    k_volB <<<512, 256, 0, stream>>>(vol, tw, A1);
    k_volC <<<512, 256, 0, stream>>>(A1, A2, tw);
    k_volD <<<512, 256, 0, stream>>>(A2, tw, Vr);
    k_fimgB<<<130, 256, 0, stream>>>(imgs, tw, B1);
    k_fimgY<<<130, 256, 0, stream>>>(B1, tw, Fi);
    k_main <<<NBTG,256, 0, stream>>>(Vr, Fi, ctf, rotm, grid, tw, resVal, resShift);
    k_final<<<NB,  256, 0, stream>>>(resVal, resShift, grid, out);
}

// Round 3
// 191.589 us; speedup vs baseline: 4.0682x; 1.6659x over previous
//
#include <hip/hip_runtime.h>
#include <math.h>
#include <float.h>

#define DD   128
#define KX   65          // D/2+1
#define NB   4
#define NTT  2
#define NG   125
#define NBTG (NB*NTT*NG) // 1000
#define WIN  24
#define H0   52

typedef float f4 __attribute__((ext_vector_type(4), aligned(8)));

__device__ __forceinline__ float2 cmul(float2 a, float2 b){
    return make_float2(a.x*b.x - a.y*b.y, a.x*b.y + a.y*b.x);
}

// tw[m] = e^{+2*pi*i*m/128}
__global__ void k_tw(float2* tw){
    int m = threadIdx.x;
    if (m < 128){
        double a = (2.0*M_PI/128.0)*(double)m;
        tw[m] = make_float2((float)cos(a), (float)sin(a));
    }
}

// Stage B: rfft along x with sinc^2 weight, radix-2 fold (x, x+64 -> k parity).
// grid 512: (z, quarter-of-y)
__global__ __launch_bounds__(256) void k_volB(const float* __restrict__ vol,
                       const float2* __restrict__ twg, float2* __restrict__ A1){
    __shared__ float sV[32*DD];
    __shared__ float2 sTw[128];
    int bid = blockIdx.x;
    int z = bid >> 2, q = bid & 3;
    int y0 = q*32;
    int tid = threadIdx.x;
    if (tid < 128) sTw[tid] = twg[tid];
    float fz = (z-64)*(1.0f/128.0f);
    for (int i = tid; i < 32*DD; i += 256){
        int y = y0 + (i >> 7), x = i & 127;
        float fy = (y-64)*(1.0f/128.0f);
        float fx = (x-64)*(1.0f/128.0f);
        float r = sqrtf(fz*fz + fy*fy + fx*fx);
        float s = (r > 0.f) ? (sinf((float)M_PI*r)/((float)M_PI*r)) : 1.0f;
        sV[i] = vol[(size_t)(z*DD + y)*DD + x] * s * s;
    }
    __syncthreads();
    // radix-2 fold over x: even k use a+b, odd k use a-b
    for (int i = tid; i < 32*64; i += 256){
        int y = i >> 6, x = i & 63;
        float a = sV[y*DD + x], bb = sV[y*DD + x + 64];
        sV[y*DD + x]      = a + bb;
        sV[y*DD + x + 64] = a - bb;
    }
    __syncthreads();
    for (int o = tid; o < 32*KX; o += 256){
        int yy = o / KX, k = o - yy*KX;
        const float* row = &sV[yy*DD + ((k & 1) ? 64 : 0)];
        float ar0=0,ai0=0,ar1=0,ai1=0,ar2=0,ai2=0,ar3=0,ai3=0;
        int i0=0, i1=k&127, i2=(2*k)&127, i3=(3*k)&127;
        int st = (4*k)&127;
        #pragma unroll
        for (int x = 0; x < 64; x += 4){
            float4 v4 = *reinterpret_cast<const float4*>(&row[x]);
            float2 e0=sTw[i0], e1=sTw[i1], e2=sTw[i2], e3=sTw[i3];
            ar0 += v4.x*e0.x; ai0 -= v4.x*e0.y;
            ar1 += v4.y*e1.x; ai1 -= v4.y*e1.y;
            ar2 += v4.z*e2.x; ai2 -= v4.z*e2.y;
            ar3 += v4.w*e3.x; ai3 -= v4.w*e3.y;
            i0=(i0+st)&127; i1=(i1+st)&127; i2=(i2+st)&127; i3=(i3+st)&127;
        }
        A1[((size_t)z*DD + y0+yy)*KX + k] = make_float2(ar0+ar1+ar2+ar3, ai0+ai1+ai2+ai3);
    }
}

// Stage C: fft along y, radix-4. grid 512: (z, class c = ky&3).
// u_c(n,k) = a + (-i)^c b + (-1)^c c2 + (i)^c d  built straight from global.
__global__ __launch_bounds__(256) void k_volC(const float2* __restrict__ A1,
                       float2* __restrict__ A2, const float2* __restrict__ twg){
    __shared__ float2 sU[32*KX];   // 16640 B
    __shared__ float2 sTw[128];
    int bid = blockIdx.x;
    int z = bid >> 2, c = bid & 3;
    int tid = threadIdx.x;
    if (tid < 128) sTw[tid] = twg[tid];
    const float2* base = A1 + (size_t)z*DD*KX;
    for (int i = tid; i < 32*KX; i += 256){
        int n = i / KX, kk = i - n*KX;
        float2 a  = base[(size_t)(n     )*KX + kk];
        float2 bb = base[(size_t)(n+32)*KX + kk];
        float2 c2 = base[(size_t)(n+64)*KX + kk];
        float2 d  = base[(size_t)(n+96)*KX + kk];
        float acx = a.x + c2.x, acy = a.y + c2.y;
        float amx = a.x - c2.x, amy = a.y - c2.y;
        float bdx = bb.x + d.x, bdy = bb.y + d.y;
        float bmx = bb.x - d.x, bmy = bb.y - d.y;
        float2 u;
        if (c == 0)      u = make_float2(acx + bdx, acy + bdy);
        else if (c == 2) u = make_float2(acx - bdx, acy - bdy);
        else if (c == 1) u = make_float2(amx + bmy, amy - bmx);   // (a-c2) - i(b-d)
        else             u = make_float2(amx - bmy, amy + bmx);   // (a-c2) + i(b-d)
        sU[i] = u;
    }
    __syncthreads();
    for (int o = tid; o < 32*KX; o += 256){
        int m = o / KX, kk = o - m*KX;
        int ky = 4*m + c;
        const float2* u = &sU[kk];
        float ar0=0,ai0=0,ar1=0,ai1=0,ar2=0,ai2=0,ar3=0,ai3=0;
        int i0=0, i1=ky&127, i2=(2*ky)&127, i3=(3*ky)&127;
        int st = (4*ky)&127;
        #pragma unroll
        for (int n = 0; n < 32; n += 4){
            float2 v0=u[(n+0)*KX], v1=u[(n+1)*KX], v2=u[(n+2)*KX], v3=u[(n+3)*KX];
            float2 e0=sTw[i0], e1=sTw[i1], e2=sTw[i2], e3=sTw[i3];
            ar0 += v0.x*e0.x + v0.y*e0.y;  ai0 += v0.y*e0.x - v0.x*e0.y;
            ar1 += v1.x*e1.x + v1.y*e1.y;  ai1 += v1.y*e1.x - v1.x*e1.y;
            ar2 += v2.x*e2.x + v2.y*e2.y;  ai2 += v2.y*e2.x - v2.x*e2.y;
            ar3 += v3.x*e3.x + v3.y*e3.y;  ai3 += v3.y*e3.x - v3.x*e3.y;
            i0=(i0+st)&127; i1=(i1+st)&127; i2=(i2+st)&127; i3=(i3+st)&127;
        }
        A2[((size_t)z*DD + ky)*KX + kk] = make_float2(ar0+ar1+ar2+ar3, ai0+ai1+ai2+ai3);
    }
}

// Stage D: fft along z, radix-4, + (-1)^{hz+hy+k} + fftshift store.
// grid 512: (ky, class c = kz&3)
__global__ __launch_bounds__(256) void k_volD(const float2* __restrict__ A2,
                       const float2* __restrict__ twg, float2* __restrict__ Vr){
    __shared__ float2 sU[32*KX];
    __shared__ float2 sTw[128];
    int bid = blockIdx.x;
    int ky = bid >> 2, c = bid & 3;
    int tid = threadIdx.x;
    if (tid < 128) sTw[tid] = twg[tid];
    const float2* base = A2 + (size_t)ky*KX;
    for (int i = tid; i < 32*KX; i += 256){
        int n = i / KX, kk = i - n*KX;
        float2 a  = base[(size_t)(n     )*DD*KX + kk];
        float2 bb = base[(size_t)(n+32)*DD*KX + kk];
        float2 c2 = base[(size_t)(n+64)*DD*KX + kk];
        float2 d  = base[(size_t)(n+96)*DD*KX + kk];
        float acx = a.x + c2.x, acy = a.y + c2.y;
        float amx = a.x - c2.x, amy = a.y - c2.y;
        float bdx = bb.x + d.x, bdy = bb.y + d.y;
        float bmx = bb.x - d.x, bmy = bb.y - d.y;
        float2 u;
        if (c == 0)      u = make_float2(acx + bdx, acy + bdy);
        else if (c == 2) u = make_float2(acx - bdx, acy - bdy);
        else if (c == 1) u = make_float2(amx + bmy, amy - bmx);
        else             u = make_float2(amx - bmy, amy + bmx);
        sU[i] = u;
    }
    __syncthreads();
    int hy = (ky + 64) & 127;
    for (int o = tid; o < 32*KX; o += 256){
        int m = o / KX, kk = o - m*KX;
        int kz = 4*m + c;
        int hz = (kz + 64) & 127;
        const float2* u = &sU[kk];
        float ar0=0,ai0=0,ar1=0,ai1=0,ar2=0,ai2=0,ar3=0,ai3=0;
        int i0=0, i1=kz&127, i2=(2*kz)&127, i3=(3*kz)&127;
        int st = (4*kz)&127;
        #pragma unroll
        for (int n = 0; n < 32; n += 4){
            float2 v0=u[(n+0)*KX], v1=u[(n+1)*KX], v2=u[(n+2)*KX], v3=u[(n+3)*KX];
            float2 e0=sTw[i0], e1=sTw[i1], e2=sTw[i2], e3=sTw[i3];
            ar0 += v0.x*e0.x + v0.y*e0.y;  ai0 += v0.y*e0.x - v0.x*e0.y;
            ar1 += v1.x*e1.x + v1.y*e1.y;  ai1 += v1.y*e1.x - v1.x*e1.y;
            ar2 += v2.x*e2.x + v2.y*e2.y;  ai2 += v2.y*e2.x - v2.x*e2.y;
            ar3 += v3.x*e3.x + v3.y*e3.y;  ai3 += v3.y*e3.x - v3.x*e3.y;
            i0=(i0+st)&127; i1=(i1+st)&127; i2=(i2+st)&127; i3=(i3+st)&127;
        }
        float sgn = ((hz + hy + kk) & 1) ? -1.f : 1.f;
        Vr[((size_t)hz*DD + hy)*KX + kk] =
            make_float2((ar0+ar1+ar2+ar3)*sgn, (ai0+ai1+ai2+ai3)*sgn);
    }
}

// Image rfft along x.  B1[b][y][kx]
__global__ __launch_bounds__(256) void k_fimgB(const float* __restrict__ imgs,
                        const float2* __restrict__ twg, float2* __restrict__ B1){
    __shared__ float2 sTw[128];
    if (threadIdx.x < 128) sTw[threadIdx.x] = twg[threadIdx.x];
    __syncthreads();
    int o = blockIdx.x*256 + threadIdx.x;
    if (o >= NB*DD*KX) return;
    int b = o / (DD*KX);
    int r = o - b*DD*KX;
    int y = r / KX, k = r - y*KX;
    const float* row = imgs + (size_t)(b*DD + y)*DD;
    float ar0=0,ai0=0,ar1=0,ai1=0,ar2=0,ai2=0,ar3=0,ai3=0;
    int i0=0, i1=k&127, i2=(2*k)&127, i3=(3*k)&127;
    int st = (4*k)&127;
    for (int x = 0; x < DD; x += 4){
        float v0=row[x], v1=row[x+1], v2=row[x+2], v3=row[x+3];
        float2 e0=sTw[i0], e1=sTw[i1], e2=sTw[i2], e3=sTw[i3];
        ar0 += v0*e0.x; ai0 -= v0*e0.y;
        ar1 += v1*e1.x; ai1 -= v1*e1.y;
        ar2 += v2*e2.x; ai2 -= v2*e2.y;
        ar3 += v3*e3.x; ai3 -= v3*e3.y;
        i0=(i0+st)&127; i1=(i1+st)&127; i2=(i2+st)&127; i3=(i3+st)&127;
    }
    B1[o] = make_float2(ar0+ar1+ar2+ar3, ai0+ai1+ai2+ai3);
}

// Image fft along y + signs + y-shift.  Fimg[b][h][kx]
__global__ __launch_bounds__(256) void k_fimgY(const float2* __restrict__ B1,
                        const float2* __restrict__ twg, float2* __restrict__ Fimg){
    __shared__ float2 sTw[128];
    if (threadIdx.x < 128) sTw[threadIdx.x] = twg[threadIdx.x];
    __syncthreads();
    int o = blockIdx.x*256 + threadIdx.x;
    if (o >= NB*DD*KX) return;
    int b = o / (DD*KX);
    int r = o - b*DD*KX;
    int h = r / KX, k = r - h*KX;
    int kky = (h + 64) & 127;
    const float2* col = B1 + (size_t)b*DD*KX + k;
    float ar0=0,ai0=0,ar1=0,ai1=0,ar2=0,ai2=0,ar3=0,ai3=0;
    int i0=0, i1=kky&127, i2=(2*kky)&127, i3=(3*kky)&127;
    int st = (4*kky)&127;
    for (int y = 0; y < DD; y += 4){
        float2 v0=col[(size_t)(y+0)*KX], v1=col[(size_t)(y+1)*KX];
        float2 v2=col[(size_t)(y+2)*KX], v3=col[(size_t)(y+3)*KX];
        float2 e0=sTw[i0], e1=sTw[i1], e2=sTw[i2], e3=sTw[i3];
        ar0 += v0.x*e0.x + v0.y*e0.y;  ai0 += v0.y*e0.x - v0.x*e0.y;
        ar1 += v1.x*e1.x + v1.y*e1.y;  ai1 += v1.y*e1.x - v1.x*e1.y;
        ar2 += v2.x*e2.x + v2.y*e2.y;  ai2 += v2.y*e2.x - v2.x*e2.y;
        ar3 += v3.x*e3.x + v3.y*e3.y;  ai3 += v3.y*e3.x - v3.x*e3.y;
        i0=(i0+st)&127; i1=(i1+st)&127; i2=(i2+st)&127; i3=(i3+st)&127;
    }
    float sgn = ((h + k)&1) ? -1.f : 1.f;
    Fimg[o] = make_float2((ar0+ar1+ar2+ar3)*sgn, (ai0+ai1+ai2+ai3)*sgn);
}

// Main: per (b,t,g): k split into two halves (k<33, k>=33); per half:
// slice-extract -> radix-4 butterfly (in place) -> partial y-IDFT (24 rows)
// writing disjoint sT columns. Then partial x-irfft (24 cols) -> argmax.
__global__ __launch_bounds__(256) void k_main(
    const float2* __restrict__ Vr, const float2* __restrict__ Fimg,
    const float* __restrict__ ctf, const float* __restrict__ rotm,
    const float* __restrict__ grid, const float2* __restrict__ twg,
    float* __restrict__ resVal, int2* __restrict__ resShift)
{
    __shared__ float2 sP[DD*33];      // 33792 B (P then u, per k-half)
    __shared__ float2 sT[WIN*KX];     // 12480 B
    __shared__ float2 sTw[128];       // 1024 B
    __shared__ float  sM[9];

    int tid = threadIdx.x;
    int blk = blockIdx.x;
    int b  = blk / (NTT*NG);
    int rr = blk - b*NTT*NG;
    int t  = rr / NG;
    int g  = rr - t*NG;

    if (tid < 128) sTw[tid] = twg[tid];
    if (tid < 9){
        int i = tid/3, k = tid - 3*i;
        const float* R  = rotm + (size_t)(b*NTT + t)*9;
        const float* Gm = grid + (size_t)g*9;
        sM[tid] = R[i*3+0]*Gm[0*3+k] + R[i*3+1]*Gm[1*3+k] + R[i*3+2]*Gm[2*3+k];
    }
    __syncthreads();

    float M00=sM[0], M01=sM[1], M10=sM[3], M11=sM[4], M20=sM[6], M21=sM[7];

    for (int half = 0; half < 2; ++half){
        const int kbase = half ? 33 : 0;
        const int Nk    = half ? 32 : 33;

        // Phase 1: central slice (trilinear, conj-flip) * ctf, conj, * fimg
        for (int idx = tid; idx < DD*Nk; idx += 256){
            int h = idx / Nk, kk = idx - h*Nk;
            int w = kbase + kk;
            float fy = (h - 64)*(1.0f/128.0f);
            float fx = w*(1.0f/128.0f);
            float rz  = M21*fy + M20*fx;
            float ryv = M11*fy + M10*fx;
            float rx  = M01*fy + M00*fx;
            bool neg = rx < 0.f;
            if (neg){ rz=-rz; ryv=-ryv; rx=-rx; }
            float zi = rz*128.f + 64.f;
            float yi = ryv*128.f + 64.f;
            float xi = rx*128.f;
            float z0f = floorf(zi), y0f = floorf(yi), x0f = floorf(xi);
            float fz2 = zi - z0f, fy2 = yi - y0f, fx2 = xi - x0f;
            int z0 = (int)z0f, y0 = (int)y0f, x0 = (int)x0f;
            // x corners: adjacent -> one aligned(8) float4 load per (z,y) row
            float wx0 = (x0 <= 64) ? (1.f - fx2) : 0.f;   // x0 >= 0 always
            float wx1 = (x0 <= 63) ? fx2 : 0.f;
            bool hi = (x0 > 63);
            int xb = hi ? 63 : x0;
            float sr = 0.f, si = 0.f;
            #pragma unroll
            for (int cc = 0; cc < 4; ++cc){
                int dz = cc>>1, dy = cc&1;
                int zc = z0+dz, yc = y0+dy;
                float wzy = (dz?fz2:1.f-fz2)*(dy?fy2:1.f-fy2);
                bool okr = (zc>=0) & (zc<DD) & (yc>=0) & (yc<DD);
                wzy = okr ? wzy : 0.f;
                int zcc = min(max(zc,0),DD-1), ycc = min(max(yc,0),DD-1);
                f4 v = *reinterpret_cast<const f4*>(&Vr[((size_t)zcc*DD + ycc)*KX + xb]);
                float c0x = hi ? v.z : v.x;
                float c0y = hi ? v.w : v.y;
                float w0 = wzy*wx0, w1 = wzy*wx1;
                sr += c0x*w0 + v.z*w1;
                si += c0y*w0 + v.w*w1;
            }
            if (neg) si = -si;
            float cf = ctf[(size_t)(b*DD + h)*KX + w];
            float pr = sr*cf, pi = si*cf;
            float2 f = Fimg[(size_t)(b*DD + h)*KX + w];
            sP[h*33 + kk] = make_float2(f.x*pr + f.y*pi, f.y*pr - f.x*pi);
        }
        __syncthreads();

        // Radix-4 butterfly in place (inverse: u_c = a + i^c b + (-1)^c c2 + (-i)^c d)
        for (int i = tid; i < 32*Nk; i += 256){
            int n = i / Nk, kk = i - n*Nk;
            int o0 = n*33 + kk;
            float2 a  = sP[o0];
            float2 bb = sP[o0 + 32*33];
            float2 c2 = sP[o0 + 64*33];
            float2 d  = sP[o0 + 96*33];
            float acx = a.x + c2.x, acy = a.y + c2.y;
            float amx = a.x - c2.x, amy = a.y - c2.y;
            float bdx = bb.x + d.x, bdy = bb.y + d.y;
            float bmx = bb.x - d.x, bmy = bb.y - d.y;
            sP[o0        ] = make_float2(acx + bdx, acy + bdy);   // c=0
            sP[o0 + 32*33] = make_float2(amx - bmy, amy + bmx);   // c=1: + i(b-d)
            sP[o0 + 64*33] = make_float2(acx - bdx, acy - bdy);   // c=2
            sP[o0 + 96*33] = make_float2(amx + bmy, amy - bmx);   // c=3: - i(b-d)
        }
        __syncthreads();

        // Phase 2: partial inverse DFT along y (24 rows), 32-length class dots
        for (int o = tid; o < WIN*Nk; o += 256){
            int a = o / Nk, kk = o - a*Nk;
            int ry = (116 + a) & 127;
            int c = ry & 3;
            const float2* u = &sP[(c*32)*33 + kk];
            float ar0=0,ai0=0,ar1=0,ai1=0,ar2=0,ai2=0,ar3=0,ai3=0;
            int i0=0, i1=ry&127, i2=(2*ry)&127, i3=(3*ry)&127;
            int st = (4*ry)&127;
            #pragma unroll
            for (int n = 0; n < 32; n += 4){
                float2 v0=u[(n+0)*33], v1=u[(n+1)*33], v2=u[(n+2)*33], v3=u[(n+3)*33];
                float2 e0=sTw[i0], e1=sTw[i1], e2=sTw[i2], e3=sTw[i3];
                ar0 += v0.x*e0.x - v0.y*e0.y;  ai0 += v0.x*e0.y + v0.y*e0.x;
                ar1 += v1.x*e1.x - v1.y*e1.y;  ai1 += v1.x*e1.y + v1.y*e1.x;
                ar2 += v2.x*e2.x - v2.y*e2.y;  ai2 += v2.x*e2.y + v2.y*e2.x;
                ar3 += v3.x*e3.x - v3.y*e3.y;  ai3 += v3.x*e3.y + v3.y*e3.x;
                i0=(i0+st)&127; i1=(i1+st)&127; i2=(i2+st)&127; i3=(i3+st)&127;
            }
            float sgn = (a & 1) ? -(1.f/128.f) : (1.f/128.f);   // (-1)^ry / 128
            sT[a*KX + kbase + kk] =
                make_float2((ar0+ar1+ar2+ar3)*sgn, (ai0+ai1+ai2+ai3)*sgn);
        }
        __syncthreads();
    }

    // Phase 3: partial irfft along x (24 needed cols)
    float* sC = reinterpret_cast<float*>(sP);
    for (int o = tid; o < WIN*WIN; o += 256){
        int a = o / WIN, bx = o - a*WIN;
        int rx = (116 + bx) & 127;
        const float2* Trow = &sT[a*KX];
        float acc0 = Trow[0].x + ((bx & 1) ? -Trow[64].x : Trow[64].x);
        float acc1 = 0.f;
        int j1 = rx, j2 = (2*rx)&127;
        int st = (2*rx)&127;
        for (int k = 1; k < 63; k += 2){
            float2 e1 = sTw[j1]; float2 T1 = Trow[k];
            float2 e2 = sTw[j2]; float2 T2 = Trow[k+1];
            acc0 += 2.f*(T1.x*e1.x - T1.y*e1.y);
            acc1 += 2.f*(T2.x*e2.x - T2.y*e2.y);
            j1=(j1+st)&127; j2=(j2+st)&127;
        }
        {
            float2 e = sTw[(63*rx)&127]; float2 T = Trow[63];
            acc0 += 2.f*(T.x*e.x - T.y*e.y);
        }
        sC[o] = (acc0+acc1)*(1.f/128.f);
    }
    __syncthreads();

    // Phase 4: argmax, row-major first occurrence tie-break
    float best = -FLT_MAX; int bidx = 0;
    for (int i = tid; i < WIN*WIN; i += 256){
        float v = sC[i];
        if (v > best){ best = v; bidx = i; }
    }
    float* sRv = sC + WIN*WIN;
    int*   sRi = reinterpret_cast<int*>(sRv + 256);
    sRv[tid] = best; sRi[tid] = bidx;
    __syncthreads();
    for (int s = 128; s > 0; s >>= 1){
        if (tid < s){
            float v2 = sRv[tid+s]; int i2 = sRi[tid+s];
            float v1 = sRv[tid];   int i1 = sRi[tid];
            if (v2 > v1 || (v2 == v1 && i2 < i1)){ sRv[tid] = v2; sRi[tid] = i2; }
        }
        __syncthreads();
    }
    if (tid == 0){
        int i = sRi[0];
        int a = i / WIN, bx = i - a*WIN;
        resVal[blk] = sRv[0];
        resShift[blk] = make_int2(H0 + bx, H0 + a);
    }
}

// Final: per-batch top-2 (stable ties), mean/std(ddof=1), erf — parallel.
__global__ __launch_bounds__(256) void k_final(const float* __restrict__ resVal,
                        const int2* __restrict__ resShift,
                        const float* __restrict__ grid, float* __restrict__ out)
{
    __shared__ float sv[256];
    __shared__ int   si[256];
    __shared__ float sr[256];
    __shared__ float sMean;
    const int N = NTT*NG;   // 250
    int b = blockIdx.x, tid = threadIdx.x;
    const float* v = resVal + (size_t)b*N;
    float myv = (tid < N) ? v[tid] : -FLT_MAX;

    sv[tid] = myv; si[tid] = (tid < N) ? tid : 0x7fffffff;
    __syncthreads();
    for (int s = 128; s > 0; s >>= 1){
        if (tid < s){
            float v2 = sv[tid+s]; int i2 = si[tid+s];
            if (v2 > sv[tid] || (v2 == sv[tid] && i2 < si[tid])){ sv[tid]=v2; si[tid]=i2; }
        }
        __syncthreads();
    }
    float v0 = sv[0]; int i0 = si[0];
    __syncthreads();

    bool act = (tid < N) && (tid != i0);
    sv[tid] = act ? myv : -FLT_MAX; si[tid] = act ? tid : 0x7fffffff;
    __syncthreads();
    for (int s = 128; s > 0; s >>= 1){
        if (tid < s){
            float v2 = sv[tid+s]; int i2 = si[tid+s];
            if (v2 > sv[tid] || (v2 == sv[tid] && i2 < si[tid])){ sv[tid]=v2; si[tid]=i2; }
        }
        __syncthreads();
    }
    float v1 = sv[0]; int i1 = si[0];
    __syncthreads();

    sr[tid] = (tid < N) ? myv : 0.f;
    __syncthreads();
    for (int s = 128; s > 0; s >>= 1){
        if (tid < s) sr[tid] += sr[tid+s];
        __syncthreads();
    }
    if (tid == 0) sMean = sr[0] / (float)N;
    __syncthreads();
    float mean = sMean;

    float d = (tid < N) ? (myv - mean) : 0.f;
    sr[tid] = d*d;
    __syncthreads();
    for (int s = 128; s > 0; s >>= 1){
        if (tid < s) sr[tid] += sr[tid+s];
        __syncthreads();
    }

    if (tid == 0){
        float stdv = sqrtf(sr[0] / (float)(N - 1));
        float vals[2] = {v0, v1};
        int   idxs[2] = {i0, i1};
        for (int k = 0; k < 2; ++k){
            out[b*2 + k] = vals[k];
            int gi = idxs[k] % NG;
            for (int j = 0; j < 9; ++j) out[8 + (b*2+k)*9 + j] = grid[(size_t)gi*9 + j];
            int2 sh = resShift[(size_t)b*N + idxs[k]];
            out[80 + (b*2+k)*2 + 0] = -((float)sh.x - 64.f)*1.5f;
            out[80 + (b*2+k)*2 + 1] = -((float)sh.y - 64.f)*1.5f;
            out[96 + b*2 + k] = 0.5f*(1.f + erff((vals[k] - mean)/(stdv*1.41421356237309515f)));
        }
    }
}

extern "C" void kernel_launch(void* const* d_in, const int* in_sizes, int n_in,
                              void* d_out, int out_size, void* d_ws, size_t ws_size,
                              hipStream_t stream)
{
    const float* vol  = (const float*)d_in[0];
    const float* imgs = (const float*)d_in[1];
    const float* ctf  = (const float*)d_in[2];
    const float* rotm = (const float*)d_in[3];
    const float* grid = (const float*)d_in[4];
    float* out = (float*)d_out;

    char* ws = (char*)d_ws;
    size_t off = 0;
    float2* tw = (float2*)(ws + off); off += 1024;
    float2* A1 = (float2*)(ws + off); off += (size_t)DD*DD*KX*sizeof(float2);
    float2* A2 = (float2*)(ws + off); off += (size_t)DD*DD*KX*sizeof(float2);
    float2* Vr = (float2*)(ws + off); off += (size_t)DD*DD*KX*sizeof(float2);
    float2* B1 = (float2*)(ws + off); off += (size_t)NB*DD*KX*sizeof(float2);
    float2* Fi = (float2*)(ws + off); off += (size_t)NB*DD*KX*sizeof(float2);
    float* resVal = (float*)(ws + off); off += (size_t)NBTG*sizeof(float);
    int2* resShift = (int2*)(ws + off); off += (size_t)NBTG*sizeof(int2);

    k_tw   <<<1,   128, 0, stream>>>(tw);
    k_volB <<<512, 256, 0, stream>>>(vol, tw, A1);
    k_volC <<<512, 256, 0, stream>>>(A1, A2, tw);
    k_volD <<<512, 256, 0, stream>>>(A2, tw, Vr);
    k_fimgB<<<130, 256, 0, stream>>>(imgs, tw, B1);
    k_fimgY<<<130, 256, 0, stream>>>(B1, tw, Fi);
    k_main <<<NBTG,256, 0, stream>>>(Vr, Fi, ctf, rotm, grid, tw, resVal, resShift);
    k_final<<<NB,  256, 0, stream>>>(resVal, resShift, grid, out);
}

// Round 4
// 152.599 us; speedup vs baseline: 5.1076x; 1.2555x over previous
//
#include <hip/hip_runtime.h>
#include <math.h>
#include <float.h>

#define DD   128
#define KX   65          // D/2+1
#define NB   4
#define NTT  2
#define NG   125
#define NBTG (NB*NTT*NG) // 1000
#define WIN  24
#define H0   52

typedef float f4 __attribute__((ext_vector_type(4), aligned(8)));

// inline twiddle table: sTw[m] = e^{+2*pi*i*m/128}
__device__ __forceinline__ void make_tw(float2* sTw, int tid){
    if (tid < 128){
        float s, c;
        sincosf((float)tid * (float)(M_PI/64.0), &s, &c);
        sTw[tid] = make_float2(c, s);
    }
}

// Stage A (fused): bid<512 -> vol rfft-x (sinc^2 weight, radix-2 fold);
//                  bid>=512 -> image rfft-x.
__global__ __launch_bounds__(256) void k_stageA(const float* __restrict__ vol,
                       const float* __restrict__ imgs,
                       float2* __restrict__ A1, float2* __restrict__ B1){
    __shared__ float sV[32*DD];
    __shared__ float2 sTw[128];
    int tid = threadIdx.x;
    int bid = blockIdx.x;
    make_tw(sTw, tid);
    __syncthreads();

    if (bid < 512){
        int z = bid >> 2, q = bid & 3;
        int y0 = q*32;
        float fz = (z-64)*(1.0f/128.0f);
        for (int i = tid; i < 32*DD; i += 256){
            int y = y0 + (i >> 7), x = i & 127;
            float fy = (y-64)*(1.0f/128.0f);
            float fx = (x-64)*(1.0f/128.0f);
            float r = sqrtf(fz*fz + fy*fy + fx*fx);
            float s = (r > 0.f) ? (sinf((float)M_PI*r)/((float)M_PI*r)) : 1.0f;
            sV[i] = vol[(size_t)(z*DD + y)*DD + x] * s * s;
        }
        __syncthreads();
        // radix-2 fold over x: even k use a+b, odd k use a-b
        for (int i = tid; i < 32*64; i += 256){
            int y = i >> 6, x = i & 63;
            float a = sV[y*DD + x], bb = sV[y*DD + x + 64];
            sV[y*DD + x]      = a + bb;
            sV[y*DD + x + 64] = a - bb;
        }
        __syncthreads();
        for (int o = tid; o < 32*KX; o += 256){
            int yy = o / KX, k = o - yy*KX;
            const float* row = &sV[yy*DD + ((k & 1) ? 64 : 0)];
            float ar0=0,ai0=0,ar1=0,ai1=0,ar2=0,ai2=0,ar3=0,ai3=0;
            int i0=0, i1=k&127, i2=(2*k)&127, i3=(3*k)&127;
            int st = (4*k)&127;
            #pragma unroll
            for (int x = 0; x < 64; x += 4){
                float4 v4 = *reinterpret_cast<const float4*>(&row[x]);
                float2 e0=sTw[i0], e1=sTw[i1], e2=sTw[i2], e3=sTw[i3];
                ar0 += v4.x*e0.x; ai0 -= v4.x*e0.y;
                ar1 += v4.y*e1.x; ai1 -= v4.y*e1.y;
                ar2 += v4.z*e2.x; ai2 -= v4.z*e2.y;
                ar3 += v4.w*e3.x; ai3 -= v4.w*e3.y;
                i0=(i0+st)&127; i1=(i1+st)&127; i2=(i2+st)&127; i3=(i3+st)&127;
            }
            A1[((size_t)z*DD + y0+yy)*KX + k] = make_float2(ar0+ar1+ar2+ar3, ai0+ai1+ai2+ai3);
        }
    } else {
        int o = (bid - 512)*256 + tid;
        if (o >= NB*DD*KX) return;
        int b = o / (DD*KX);
        int r = o - b*DD*KX;
        int y = r / KX, k = r - y*KX;
        const float* row = imgs + (size_t)(b*DD + y)*DD;
        float ar0=0,ai0=0,ar1=0,ai1=0,ar2=0,ai2=0,ar3=0,ai3=0;
        int i0=0, i1=k&127, i2=(2*k)&127, i3=(3*k)&127;
        int st = (4*k)&127;
        for (int x = 0; x < DD; x += 4){
            float v0=row[x], v1=row[x+1], v2=row[x+2], v3=row[x+3];
            float2 e0=sTw[i0], e1=sTw[i1], e2=sTw[i2], e3=sTw[i3];
            ar0 += v0*e0.x; ai0 -= v0*e0.y;
            ar1 += v1*e1.x; ai1 -= v1*e1.y;
            ar2 += v2*e2.x; ai2 -= v2*e2.y;
            ar3 += v3*e3.x; ai3 -= v3*e3.y;
            i0=(i0+st)&127; i1=(i1+st)&127; i2=(i2+st)&127; i3=(i3+st)&127;
        }
        B1[o] = make_float2(ar0+ar1+ar2+ar3, ai0+ai1+ai2+ai3);
    }
}

// Stage B (fused): bid<512 -> vol fft-y radix-4 (class per block);
//                  bid>=512 -> image fft-y + signs + ctf premul -> Fc.
__global__ __launch_bounds__(256) void k_stageB(const float2* __restrict__ A1,
                       const float* __restrict__ ctf, const float2* __restrict__ B1,
                       float2* __restrict__ A2, float2* __restrict__ Fc){
    __shared__ float2 sU[32*KX];   // 16640 B
    __shared__ float2 sTw[128];
    int tid = threadIdx.x;
    int bid = blockIdx.x;
    make_tw(sTw, tid);
    __syncthreads();

    if (bid < 512){
        int z = bid >> 2, c = bid & 3;
        const float2* base = A1 + (size_t)z*DD*KX;
        for (int i = tid; i < 32*KX; i += 256){
            int n = i / KX, kk = i - n*KX;
            float2 a  = base[(size_t)(n     )*KX + kk];
            float2 bb = base[(size_t)(n+32)*KX + kk];
            float2 c2 = base[(size_t)(n+64)*KX + kk];
            float2 d  = base[(size_t)(n+96)*KX + kk];
            float acx = a.x + c2.x, acy = a.y + c2.y;
            float amx = a.x - c2.x, amy = a.y - c2.y;
            float bdx = bb.x + d.x, bdy = bb.y + d.y;
            float bmx = bb.x - d.x, bmy = bb.y - d.y;
            float2 u;
            if (c == 0)      u = make_float2(acx + bdx, acy + bdy);
            else if (c == 2) u = make_float2(acx - bdx, acy - bdy);
            else if (c == 1) u = make_float2(amx + bmy, amy - bmx);   // (a-c2) - i(b-d)
            else             u = make_float2(amx - bmy, amy + bmx);   // (a-c2) + i(b-d)
            sU[i] = u;
        }
        __syncthreads();
        for (int o = tid; o < 32*KX; o += 256){
            int m = o / KX, kk = o - m*KX;
            int ky = 4*m + c;
            const float2* u = &sU[kk];
            float ar0=0,ai0=0,ar1=0,ai1=0,ar2=0,ai2=0,ar3=0,ai3=0;
            int i0=0, i1=ky&127, i2=(2*ky)&127, i3=(3*ky)&127;
            int st = (4*ky)&127;
            #pragma unroll
            for (int n = 0; n < 32; n += 4){
                float2 v0=u[(n+0)*KX], v1=u[(n+1)*KX], v2=u[(n+2)*KX], v3=u[(n+3)*KX];
                float2 e0=sTw[i0], e1=sTw[i1], e2=sTw[i2], e3=sTw[i3];
                ar0 += v0.x*e0.x + v0.y*e0.y;  ai0 += v0.y*e0.x - v0.x*e0.y;
                ar1 += v1.x*e1.x + v1.y*e1.y;  ai1 += v1.y*e1.x - v1.x*e1.y;
                ar2 += v2.x*e2.x + v2.y*e2.y;  ai2 += v2.y*e2.x - v2.x*e2.y;
                ar3 += v3.x*e3.x + v3.y*e3.y;  ai3 += v3.y*e3.x - v3.x*e3.y;
                i0=(i0+st)&127; i1=(i1+st)&127; i2=(i2+st)&127; i3=(i3+st)&127;
            }
            A2[((size_t)z*DD + ky)*KX + kk] = make_float2(ar0+ar1+ar2+ar3, ai0+ai1+ai2+ai3);
        }
    } else {
        int o = (bid - 512)*256 + tid;
        if (o >= NB*DD*KX) return;
        int b = o / (DD*KX);
        int r = o - b*DD*KX;
        int h = r / KX, k = r - h*KX;
        int kky = (h + 64) & 127;
        const float2* col = B1 + (size_t)b*DD*KX + k;
        float ar0=0,ai0=0,ar1=0,ai1=0,ar2=0,ai2=0,ar3=0,ai3=0;
        int i0=0, i1=kky&127, i2=(2*kky)&127, i3=(3*kky)&127;
        int st = (4*kky)&127;
        for (int y = 0; y < DD; y += 4){
            float2 v0=col[(size_t)(y+0)*KX], v1=col[(size_t)(y+1)*KX];
            float2 v2=col[(size_t)(y+2)*KX], v3=col[(size_t)(y+3)*KX];
            float2 e0=sTw[i0], e1=sTw[i1], e2=sTw[i2], e3=sTw[i3];
            ar0 += v0.x*e0.x + v0.y*e0.y;  ai0 += v0.y*e0.x - v0.x*e0.y;
            ar1 += v1.x*e1.x + v1.y*e1.y;  ai1 += v1.y*e1.x - v1.x*e1.y;
            ar2 += v2.x*e2.x + v2.y*e2.y;  ai2 += v2.y*e2.x - v2.x*e2.y;
            ar3 += v3.x*e3.x + v3.y*e3.y;  ai3 += v3.y*e3.x - v3.x*e3.y;
            i0=(i0+st)&127; i1=(i1+st)&127; i2=(i2+st)&127; i3=(i3+st)&127;
        }
        float sgn = ((h + k)&1) ? -1.f : 1.f;
        float cf = ctf[o];
        Fc[o] = make_float2((ar0+ar1+ar2+ar3)*sgn*cf, (ai0+ai1+ai2+ai3)*sgn*cf);
    }
}

// Stage D: fft along z, radix-4, + (-1)^{hz+hy+k} + fftshift store.
// grid 512: (ky, class c = kz&3)
__global__ __launch_bounds__(256) void k_volD(const float2* __restrict__ A2,
                       float2* __restrict__ Vr){
    __shared__ float2 sU[32*KX];
    __shared__ float2 sTw[128];
    int tid = threadIdx.x;
    int bid = blockIdx.x;
    int ky = bid >> 2, c = bid & 3;
    make_tw(sTw, tid);
    __syncthreads();
    const float2* base = A2 + (size_t)ky*KX;
    for (int i = tid; i < 32*KX; i += 256){
        int n = i / KX, kk = i - n*KX;
        float2 a  = base[(size_t)(n     )*DD*KX + kk];
        float2 bb = base[(size_t)(n+32)*DD*KX + kk];
        float2 c2 = base[(size_t)(n+64)*DD*KX + kk];
        float2 d  = base[(size_t)(n+96)*DD*KX + kk];
        float acx = a.x + c2.x, acy = a.y + c2.y;
        float amx = a.x - c2.x, amy = a.y - c2.y;
        float bdx = bb.x + d.x, bdy = bb.y + d.y;
        float bmx = bb.x - d.x, bmy = bb.y - d.y;
        float2 u;
        if (c == 0)      u = make_float2(acx + bdx, acy + bdy);
        else if (c == 2) u = make_float2(acx - bdx, acy - bdy);
        else if (c == 1) u = make_float2(amx + bmy, amy - bmx);
        else             u = make_float2(amx - bmy, amy + bmx);
        sU[i] = u;
    }
    __syncthreads();
    int hy = (ky + 64) & 127;
    for (int o = tid; o < 32*KX; o += 256){
        int m = o / KX, kk = o - m*KX;
        int kz = 4*m + c;
        int hz = (kz + 64) & 127;
        const float2* u = &sU[kk];
        float ar0=0,ai0=0,ar1=0,ai1=0,ar2=0,ai2=0,ar3=0,ai3=0;
        int i0=0, i1=kz&127, i2=(2*kz)&127, i3=(3*kz)&127;
        int st = (4*kz)&127;
        #pragma unroll
        for (int n = 0; n < 32; n += 4){
            float2 v0=u[(n+0)*KX], v1=u[(n+1)*KX], v2=u[(n+2)*KX], v3=u[(n+3)*KX];
            float2 e0=sTw[i0], e1=sTw[i1], e2=sTw[i2], e3=sTw[i3];
            ar0 += v0.x*e0.x + v0.y*e0.y;  ai0 += v0.y*e0.x - v0.x*e0.y;
            ar1 += v1.x*e1.x + v1.y*e1.y;  ai1 += v1.y*e1.x - v1.x*e1.y;
            ar2 += v2.x*e2.x + v2.y*e2.y;  ai2 += v2.y*e2.x - v2.x*e2.y;
            ar3 += v3.x*e3.x + v3.y*e3.y;  ai3 += v3.y*e3.x - v3.x*e3.y;
            i0=(i0+st)&127; i1=(i1+st)&127; i2=(i2+st)&127; i3=(i3+st)&127;
        }
        float sgn = ((hz + hy + kk) & 1) ? -1.f : 1.f;
        Vr[((size_t)hz*DD + hy)*KX + kk] =
            make_float2((ar0+ar1+ar2+ar3)*sgn, (ai0+ai1+ai2+ai3)*sgn);
    }
}

// Main: per (b,t,g): k in 4 chunks (17,17,17,14); per chunk:
// slice-extract*Fc -> radix-4 butterfly -> partial y-IDFT (2 rows/thread)
// into disjoint sT columns. Then partial x-irfft (24 cols) -> argmax.
__global__ __launch_bounds__(256,5) void k_main(
    const float2* __restrict__ Vr, const float2* __restrict__ Fc,
    const float* __restrict__ rotm, const float* __restrict__ grid,
    float* __restrict__ resVal, int2* __restrict__ resShift)
{
    __shared__ float2 sP[DD*17];      // 17408 B
    __shared__ float2 sT[WIN*KX];     // 12480 B
    __shared__ float2 sTw[128];       // 1024 B
    __shared__ float  sM[9];

    int tid = threadIdx.x;
    int blk = blockIdx.x;
    int b  = blk / (NTT*NG);
    int rr = blk - b*NTT*NG;
    int t  = rr / NG;
    int g  = rr - t*NG;

    make_tw(sTw, tid);
    if (tid < 9){
        int i = tid/3, k = tid - 3*i;
        const float* R  = rotm + (size_t)(b*NTT + t)*9;
        const float* Gm = grid + (size_t)g*9;
        sM[tid] = R[i*3+0]*Gm[0*3+k] + R[i*3+1]*Gm[1*3+k] + R[i*3+2]*Gm[2*3+k];
    }
    __syncthreads();

    float M00=sM[0], M01=sM[1], M10=sM[3], M11=sM[4], M20=sM[6], M21=sM[7];

    const int KB[4]  = {0,17,34,51};
    const int NKc[4] = {17,17,17,14};
    #pragma unroll
    for (int cc = 0; cc < 4; ++cc){
        const int kbase = KB[cc];
        const int Nk    = NKc[cc];

        // Phase 1: central slice (trilinear, conj-flip), * Fc (= fimg*ctf), conj
        for (int idx = tid; idx < DD*Nk; idx += 256){
            int h = idx / Nk, kk = idx - h*Nk;
            int w = kbase + kk;
            float fy = (h - 64)*(1.0f/128.0f);
            float fx = w*(1.0f/128.0f);
            float rz  = M21*fy + M20*fx;
            float ryv = M11*fy + M10*fx;
            float rx  = M01*fy + M00*fx;
            bool neg = rx < 0.f;
            if (neg){ rz=-rz; ryv=-ryv; rx=-rx; }
            float zi = rz*128.f + 64.f;
            float yi = ryv*128.f + 64.f;
            float xi = rx*128.f;
            float z0f = floorf(zi), y0f = floorf(yi), x0f = floorf(xi);
            float fz2 = zi - z0f, fy2 = yi - y0f, fx2 = xi - x0f;
            int z0 = (int)z0f, y0 = (int)y0f, x0 = (int)x0f;
            float wx0 = (x0 <= 64) ? (1.f - fx2) : 0.f;   // x0 >= 0 always
            float wx1 = (x0 <= 63) ? fx2 : 0.f;
            bool hi = (x0 > 63);
            int xb = hi ? 63 : x0;
            float sr = 0.f, si = 0.f;
            #pragma unroll
            for (int c4 = 0; c4 < 4; ++c4){
                int dz = c4>>1, dy = c4&1;
                int zc = z0+dz, yc = y0+dy;
                float wzy = (dz?fz2:1.f-fz2)*(dy?fy2:1.f-fy2);
                bool okr = (zc>=0) & (zc<DD) & (yc>=0) & (yc<DD);
                wzy = okr ? wzy : 0.f;
                int zcc = min(max(zc,0),DD-1), ycc = min(max(yc,0),DD-1);
                f4 v = *reinterpret_cast<const f4*>(&Vr[((size_t)zcc*DD + ycc)*KX + xb]);
                float c0x = hi ? v.z : v.x;
                float c0y = hi ? v.w : v.y;
                float w0 = wzy*wx0, w1 = wzy*wx1;
                sr += c0x*w0 + v.z*w1;
                si += c0y*w0 + v.w*w1;
            }
            if (neg) si = -si;
            float2 f = Fc[(size_t)(b*DD + h)*KX + w];
            sP[h*17 + kk] = make_float2(f.x*sr + f.y*si, f.y*sr - f.x*si);
        }
        __syncthreads();

        // Radix-4 butterfly (inverse: u_c = a + i^c b + (-1)^c c2 + (-i)^c d)
        for (int i = tid; i < 32*Nk; i += 256){
            int n = i / Nk, kk = i - n*Nk;
            int o0 = n*17 + kk;
            float2 a  = sP[o0];
            float2 bb = sP[o0 + 32*17];
            float2 c2 = sP[o0 + 64*17];
            float2 d  = sP[o0 + 96*17];
            float acx = a.x + c2.x, acy = a.y + c2.y;
            float amx = a.x - c2.x, amy = a.y - c2.y;
            float bdx = bb.x + d.x, bdy = bb.y + d.y;
            float bmx = bb.x - d.x, bmy = bb.y - d.y;
            sP[o0        ] = make_float2(acx + bdx, acy + bdy);   // c=0
            sP[o0 + 32*17] = make_float2(amx - bmy, amy + bmx);   // c=1: + i(b-d)
            sP[o0 + 64*17] = make_float2(acx - bdx, acy - bdy);   // c=2
            sP[o0 + 96*17] = make_float2(amx + bmy, amy - bmx);   // c=3: - i(b-d)
        }
        __syncthreads();

        // Phase 2: partial inverse y-DFT; thread computes rows a=ap and a=ap+12
        // (ry1=116+ap, ry2=ap, same class c=ap&3, shared u column)
        for (int o = tid; o < 12*Nk; o += 256){
            int ap = o / Nk, kk = o - ap*Nk;
            int ry1 = 116 + ap;
            int ry2 = ap;
            int c = ap & 3;
            const float2* u = &sP[(c*32)*17 + kk];
            float a1r0=0,a1i0=0,a1r1=0,a1i1=0;
            float a2r0=0,a2i0=0,a2r1=0,a2i1=0;
            int p10 = 0, p11 = ry1 & 127;
            int p20 = 0, p21 = ry2 & 127;
            int st1 = (2*ry1) & 127, st2 = (2*ry2) & 127;
            #pragma unroll
            for (int n = 0; n < 32; n += 2){
                float2 v0 = u[(n+0)*17], v1 = u[(n+1)*17];
                float2 e10 = sTw[p10], e11 = sTw[p11];
                float2 e20 = sTw[p20], e21 = sTw[p21];
                a1r0 += v0.x*e10.x - v0.y*e10.y;  a1i0 += v0.x*e10.y + v0.y*e10.x;
                a1r1 += v1.x*e11.x - v1.y*e11.y;  a1i1 += v1.x*e11.y + v1.y*e11.x;
                a2r0 += v0.x*e20.x - v0.y*e20.y;  a2i0 += v0.x*e20.y + v0.y*e20.x;
                a2r1 += v1.x*e21.x - v1.y*e21.y;  a2i1 += v1.x*e21.y + v1.y*e21.x;
                p10=(p10+st1)&127; p11=(p11+st1)&127;
                p20=(p20+st2)&127; p21=(p21+st2)&127;
            }
            float sgn = (ap & 1) ? -(1.f/128.f) : (1.f/128.f);   // (-1)^ry / 128
            sT[(ap   )*KX + kbase + kk] = make_float2((a1r0+a1r1)*sgn, (a1i0+a1i1)*sgn);
            sT[(ap+12)*KX + kbase + kk] = make_float2((a2r0+a2r1)*sgn, (a2i0+a2i1)*sgn);
        }
        __syncthreads();
    }

    // Phase 3: partial irfft along x (24 needed cols)
    float* sC = reinterpret_cast<float*>(sP);
    for (int o = tid; o < WIN*WIN; o += 256){
        int a = o / WIN, bx = o - a*WIN;
        int rx = (116 + bx) & 127;
        const float2* Trow = &sT[a*KX];
        float acc0 = Trow[0].x + ((bx & 1) ? -Trow[64].x : Trow[64].x);
        float acc1 = 0.f;
        int j1 = rx, j2 = (2*rx)&127;
        int st = (2*rx)&127;
        for (int k = 1; k < 63; k += 2){
            float2 e1 = sTw[j1]; float2 T1 = Trow[k];
            float2 e2 = sTw[j2]; float2 T2 = Trow[k+1];
            acc0 += 2.f*(T1.x*e1.x - T1.y*e1.y);
            acc1 += 2.f*(T2.x*e2.x - T2.y*e2.y);
            j1=(j1+st)&127; j2=(j2+st)&127;
        }
        {
            float2 e = sTw[(63*rx)&127]; float2 T = Trow[63];
            acc0 += 2.f*(T.x*e.x - T.y*e.y);
        }
        sC[o] = (acc0+acc1)*(1.f/128.f);
    }
    __syncthreads();

    // Phase 4: argmax, row-major first occurrence tie-break
    float best = -FLT_MAX; int bidx = 0;
    for (int i = tid; i < WIN*WIN; i += 256){
        float v = sC[i];
        if (v > best){ best = v; bidx = i; }
    }
    float* sRv = sC + WIN*WIN;
    int*   sRi = reinterpret_cast<int*>(sRv + 256);
    sRv[tid] = best; sRi[tid] = bidx;
    __syncthreads();
    for (int s = 128; s > 0; s >>= 1){
        if (tid < s){
            float v2 = sRv[tid+s]; int i2 = sRi[tid+s];
            float v1 = sRv[tid];   int i1 = sRi[tid];
            if (v2 > v1 || (v2 == v1 && i2 < i1)){ sRv[tid] = v2; sRi[tid] = i2; }
        }
        __syncthreads();
    }
    if (tid == 0){
        int i = sRi[0];
        int a = i / WIN, bx = i - a*WIN;
        resVal[blk] = sRv[0];
        resShift[blk] = make_int2(H0 + bx, H0 + a);
    }
}

// Final: per-batch top-2 (stable ties), mean/std(ddof=1), erf — parallel.
__global__ __launch_bounds__(256) void k_final(const float* __restrict__ resVal,
                        const int2* __restrict__ resShift,
                        const float* __restrict__ grid, float* __restrict__ out)
{
    __shared__ float sv[256];
    __shared__ int   si[256];
    __shared__ float sr[256];
    __shared__ float sMean;
    const int N = NTT*NG;   // 250
    int b = blockIdx.x, tid = threadIdx.x;
    const float* v = resVal + (size_t)b*N;
    float myv = (tid < N) ? v[tid] : -FLT_MAX;

    sv[tid] = myv; si[tid] = (tid < N) ? tid : 0x7fffffff;
    __syncthreads();
    for (int s = 128; s > 0; s >>= 1){
        if (tid < s){
            float v2 = sv[tid+s]; int i2 = si[tid+s];
            if (v2 > sv[tid] || (v2 == sv[tid] && i2 < si[tid])){ sv[tid]=v2; si[tid]=i2; }
        }
        __syncthreads();
    }
    float v0 = sv[0]; int i0 = si[0];
    __syncthreads();

    bool act = (tid < N) && (tid != i0);
    sv[tid] = act ? myv : -FLT_MAX; si[tid] = act ? tid : 0x7fffffff;
    __syncthreads();
    for (int s = 128; s > 0; s >>= 1){
        if (tid < s){
            float v2 = sv[tid+s]; int i2 = si[tid+s];
            if (v2 > sv[tid] || (v2 == sv[tid] && i2 < si[tid])){ sv[tid]=v2; si[tid]=i2; }
        }
        __syncthreads();
    }
    float v1 = sv[0]; int i1 = si[0];
    __syncthreads();

    sr[tid] = (tid < N) ? myv : 0.f;
    __syncthreads();
    for (int s = 128; s > 0; s >>= 1){
        if (tid < s) sr[tid] += sr[tid+s];
        __syncthreads();
    }
    if (tid == 0) sMean = sr[0] / (float)N;
    __syncthreads();
    float mean = sMean;

    float d = (tid < N) ? (myv - mean) : 0.f;
    sr[tid] = d*d;
    __syncthreads();
    for (int s = 128; s > 0; s >>= 1){
        if (tid < s) sr[tid] += sr[tid+s];
        __syncthreads();
    }

    if (tid == 0){
        float stdv = sqrtf(sr[0] / (float)(N - 1));
        float vals[2] = {v0, v1};
        int   idxs[2] = {i0, i1};
        for (int k = 0; k < 2; ++k){
            out[b*2 + k] = vals[k];
            int gi = idxs[k] % NG;
            for (int j = 0; j < 9; ++j) out[8 + (b*2+k)*9 + j] = grid[(size_t)gi*9 + j];
            int2 sh = resShift[(size_t)b*N + idxs[k]];
            out[80 + (b*2+k)*2 + 0] = -((float)sh.x - 64.f)*1.5f;
            out[80 + (b*2+k)*2 + 1] = -((float)sh.y - 64.f)*1.5f;
            out[96 + b*2 + k] = 0.5f*(1.f + erff((vals[k] - mean)/(stdv*1.41421356237309515f)));
        }
    }
}

extern "C" void kernel_launch(void* const* d_in, const int* in_sizes, int n_in,
                              void* d_out, int out_size, void* d_ws, size_t ws_size,
                              hipStream_t stream)
{
    const float* vol  = (const float*)d_in[0];
    const float* imgs = (const float*)d_in[1];
    const float* ctf  = (const float*)d_in[2];
    const float* rotm = (const float*)d_in[3];
    const float* grid = (const float*)d_in[4];
    float* out = (float*)d_out;

    char* ws = (char*)d_ws;
    size_t off = 0;
    float2* A1 = (float2*)(ws + off); off += (size_t)DD*DD*KX*sizeof(float2);
    float2* A2 = (float2*)(ws + off); off += (size_t)DD*DD*KX*sizeof(float2);
    float2* Vr = (float2*)(ws + off); off += (size_t)DD*DD*KX*sizeof(float2);
    float2* B1 = (float2*)(ws + off); off += (size_t)NB*DD*KX*sizeof(float2);
    float2* Fc = (float2*)(ws + off); off += (size_t)NB*DD*KX*sizeof(float2);
    float* resVal = (float*)(ws + off); off += (size_t)NBTG*sizeof(float);
    int2* resShift = (int2*)(ws + off); off += (size_t)NBTG*sizeof(int2);

    k_stageA<<<642, 256, 0, stream>>>(vol, imgs, A1, B1);
    k_stageB<<<642, 256, 0, stream>>>(A1, ctf, B1, A2, Fc);
    k_volD  <<<512, 256, 0, stream>>>(A2, Vr);
    k_main  <<<NBTG,256, 0, stream>>>(Vr, Fc, rotm, grid, resVal, resShift);
    k_final <<<NB,  256, 0, stream>>>(resVal, resShift, grid, out);
}

// Round 5
// 129.834 us; speedup vs baseline: 6.0032x; 1.1753x over previous
//
#include <hip/hip_runtime.h>
#include <math.h>
#include <float.h>

#define DD   128
#define KX   65          // D/2+1
#define NB   4
#define NTT  2
#define NG   125
#define NBTG (NB*NTT*NG) // 1000
#define WIN  24
#define H0   52

typedef float f4 __attribute__((ext_vector_type(4), aligned(8)));

__device__ __forceinline__ float2 cmul(float2 a, float2 b){
    return make_float2(a.x*b.x - a.y*b.y, a.x*b.y + a.y*b.x);
}

// inline twiddle table: sTw[m] = e^{+2*pi*i*m/128}
__device__ __forceinline__ void make_tw(float2* sTw, int tid){
    if (tid < 128){
        float s, c;
        sincosf((float)tid * (float)(M_PI/64.0), &s, &c);
        sTw[tid] = make_float2(c, s);
    }
}

// Stage A (fused): bid<512 -> vol rfft-x (sinc^2 weight, radix-2 fold);
//                  bid>=512 -> image rfft-x.
__global__ __launch_bounds__(256) void k_stageA(const float* __restrict__ vol,
                       const float* __restrict__ imgs,
                       float2* __restrict__ A1, float2* __restrict__ B1){
    __shared__ float sV[32*DD];
    __shared__ float2 sTw[128];
    int tid = threadIdx.x;
    int bid = blockIdx.x;
    make_tw(sTw, tid);
    __syncthreads();

    if (bid < 512){
        int z = bid >> 2, q = bid & 3;
        int y0 = q*32;
        float fz = (z-64)*(1.0f/128.0f);
        for (int i = tid; i < 32*DD; i += 256){
            int y = y0 + (i >> 7), x = i & 127;
            float fy = (y-64)*(1.0f/128.0f);
            float fx = (x-64)*(1.0f/128.0f);
            float r = sqrtf(fz*fz + fy*fy + fx*fx);
            float s = (r > 0.f) ? (sinf((float)M_PI*r)/((float)M_PI*r)) : 1.0f;
            sV[i] = vol[(size_t)(z*DD + y)*DD + x] * s * s;
        }
        __syncthreads();
        // radix-2 fold over x: even k use a+b, odd k use a-b
        for (int i = tid; i < 32*64; i += 256){
            int y = i >> 6, x = i & 63;
            float a = sV[y*DD + x], bb = sV[y*DD + x + 64];
            sV[y*DD + x]      = a + bb;
            sV[y*DD + x + 64] = a - bb;
        }
        __syncthreads();
        for (int o = tid; o < 32*KX; o += 256){
            int yy = o / KX, k = o - yy*KX;
            const float* row = &sV[yy*DD + ((k & 1) ? 64 : 0)];
            float ar0=0,ai0=0,ar1=0,ai1=0,ar2=0,ai2=0,ar3=0,ai3=0;
            int i0=0, i1=k&127, i2=(2*k)&127, i3=(3*k)&127;
            int st = (4*k)&127;
            #pragma unroll
            for (int x = 0; x < 64; x += 4){
                float4 v4 = *reinterpret_cast<const float4*>(&row[x]);
                float2 e0=sTw[i0], e1=sTw[i1], e2=sTw[i2], e3=sTw[i3];
                ar0 += v4.x*e0.x; ai0 -= v4.x*e0.y;
                ar1 += v4.y*e1.x; ai1 -= v4.y*e1.y;
                ar2 += v4.z*e2.x; ai2 -= v4.z*e2.y;
                ar3 += v4.w*e3.x; ai3 -= v4.w*e3.y;
                i0=(i0+st)&127; i1=(i1+st)&127; i2=(i2+st)&127; i3=(i3+st)&127;
            }
            A1[((size_t)z*DD + y0+yy)*KX + k] = make_float2(ar0+ar1+ar2+ar3, ai0+ai1+ai2+ai3);
        }
    } else {
        int o = (bid - 512)*256 + tid;
        if (o >= NB*DD*KX) return;
        int b = o / (DD*KX);
        int r = o - b*DD*KX;
        int y = r / KX, k = r - y*KX;
        const float* row = imgs + (size_t)(b*DD + y)*DD;
        float ar0=0,ai0=0,ar1=0,ai1=0,ar2=0,ai2=0,ar3=0,ai3=0;
        int i0=0, i1=k&127, i2=(2*k)&127, i3=(3*k)&127;
        int st = (4*k)&127;
        for (int x = 0; x < DD; x += 4){
            float v0=row[x], v1=row[x+1], v2=row[x+2], v3=row[x+3];
            float2 e0=sTw[i0], e1=sTw[i1], e2=sTw[i2], e3=sTw[i3];
            ar0 += v0*e0.x; ai0 -= v0*e0.y;
            ar1 += v1*e1.x; ai1 -= v1*e1.y;
            ar2 += v2*e2.x; ai2 -= v2*e2.y;
            ar3 += v3*e3.x; ai3 -= v3*e3.y;
            i0=(i0+st)&127; i1=(i1+st)&127; i2=(i2+st)&127; i3=(i3+st)&127;
        }
        B1[o] = make_float2(ar0+ar1+ar2+ar3, ai0+ai1+ai2+ai3);
    }
}

// Stage B (fused): bid<512 -> vol fft-y radix-4 x2 levels (class per block);
//                  bid>=512 -> image fft-y + signs + ctf premul -> Fc.
__global__ __launch_bounds__(256) void k_stageB(const float2* __restrict__ A1,
                       const float* __restrict__ ctf, const float2* __restrict__ B1,
                       float2* __restrict__ A2, float2* __restrict__ Fc){
    __shared__ float2 sU[32*KX];   // 16640 B
    __shared__ float2 sTw[128];
    int tid = threadIdx.x;
    int bid = blockIdx.x;
    make_tw(sTw, tid);
    __syncthreads();

    if (bid < 512){
        int z = bid >> 2, c = bid & 3;
        const float2* base = A1 + (size_t)z*DD*KX;
        // level 1: u_c[n'] built straight from global (forward signs)
        for (int i = tid; i < 32*KX; i += 256){
            int n = i / KX, kk = i - n*KX;
            float2 a  = base[(size_t)(n     )*KX + kk];
            float2 bb = base[(size_t)(n+32)*KX + kk];
            float2 c2 = base[(size_t)(n+64)*KX + kk];
            float2 d  = base[(size_t)(n+96)*KX + kk];
            float acx = a.x + c2.x, acy = a.y + c2.y;
            float amx = a.x - c2.x, amy = a.y - c2.y;
            float bdx = bb.x + d.x, bdy = bb.y + d.y;
            float bmx = bb.x - d.x, bmy = bb.y - d.y;
            float2 u;
            if (c == 0)      u = make_float2(acx + bdx, acy + bdy);
            else if (c == 2) u = make_float2(acx - bdx, acy - bdy);
            else if (c == 1) u = make_float2(amx + bmy, amy - bmx);   // (a-c2) - i(b-d)
            else             u = make_float2(amx - bmy, amy + bmx);   // (a-c2) + i(b-d)
            sU[i] = u;
        }
        __syncthreads();
        // level 2 in place (forward): v_s[n2] = sum_j u[n2+8j] conj(w)^{cj} (-i)^{sj}
        float2 w1 = sTw[(8*c)&127];  w1.y = -w1.y;
        float2 w2 = sTw[(16*c)&127]; w2.y = -w2.y;
        float2 w3 = sTw[(24*c)&127]; w3.y = -w3.y;
        for (int i = tid; i < 8*KX; i += 256){
            int n2 = i / KX, kk = i - n2*KX;
            int b0 = n2*KX + kk;
            float2 u0 = sU[b0], u1 = sU[b0+8*KX], u2 = sU[b0+16*KX], u3 = sU[b0+24*KX];
            float2 t1 = cmul(u1,w1), t2 = cmul(u2,w2), t3 = cmul(u3,w3);
            float2 p = make_float2(u0.x+t2.x, u0.y+t2.y);
            float2 q = make_float2(u0.x-t2.x, u0.y-t2.y);
            float2 r = make_float2(t1.x+t3.x, t1.y+t3.y);
            float2 s = make_float2(t1.x-t3.x, t1.y-t3.y);
            sU[b0       ] = make_float2(p.x+r.x, p.y+r.y);   // s=0
            sU[b0+ 8*KX ] = make_float2(q.x+s.y, q.y-s.x);   // s=1: q - i s
            sU[b0+16*KX ] = make_float2(p.x-r.x, p.y-r.y);   // s=2
            sU[b0+24*KX ] = make_float2(q.x-s.y, q.y+s.x);   // s=3: q + i s
        }
        __syncthreads();
        // 8-term dots
        for (int o = tid; o < 32*KX; o += 256){
            int m = o / KX, kk = o - m*KX;
            int ky = 4*m + c;
            int s4 = m & 3;
            const float2* v = &sU[(8*s4)*KX + kk];
            float ar0=0,ai0=0,ar1=0,ai1=0;
            int j = 0;
            #pragma unroll
            for (int n2 = 0; n2 < 8; n2 += 2){
                float2 v0 = v[n2*KX], v1 = v[(n2+1)*KX];
                float2 e0 = sTw[j]; int jn = (j + ky)&127;
                float2 e1 = sTw[jn];
                ar0 += v0.x*e0.x + v0.y*e0.y;  ai0 += v0.y*e0.x - v0.x*e0.y;
                ar1 += v1.x*e1.x + v1.y*e1.y;  ai1 += v1.y*e1.x - v1.x*e1.y;
                j = (jn + ky)&127;
            }
            A2[((size_t)z*DD + ky)*KX + kk] = make_float2(ar0+ar1, ai0+ai1);
        }
    } else {
        int o = (bid - 512)*256 + tid;
        if (o >= NB*DD*KX) return;
        int b = o / (DD*KX);
        int r = o - b*DD*KX;
        int h = r / KX, k = r - h*KX;
        int kky = (h + 64) & 127;
        const float2* col = B1 + (size_t)b*DD*KX + k;
        float ar0=0,ai0=0,ar1=0,ai1=0,ar2=0,ai2=0,ar3=0,ai3=0;
        int i0=0, i1=kky&127, i2=(2*kky)&127, i3=(3*kky)&127;
        int st = (4*kky)&127;
        for (int y = 0; y < DD; y += 4){
            float2 v0=col[(size_t)(y+0)*KX], v1=col[(size_t)(y+1)*KX];
            float2 v2=col[(size_t)(y+2)*KX], v3=col[(size_t)(y+3)*KX];
            float2 e0=sTw[i0], e1=sTw[i1], e2=sTw[i2], e3=sTw[i3];
            ar0 += v0.x*e0.x + v0.y*e0.y;  ai0 += v0.y*e0.x - v0.x*e0.y;
            ar1 += v1.x*e1.x + v1.y*e1.y;  ai1 += v1.y*e1.x - v1.x*e1.y;
            ar2 += v2.x*e2.x + v2.y*e2.y;  ai2 += v2.y*e2.x - v2.x*e2.y;
            ar3 += v3.x*e3.x + v3.y*e3.y;  ai3 += v3.y*e3.x - v3.x*e3.y;
            i0=(i0+st)&127; i1=(i1+st)&127; i2=(i2+st)&127; i3=(i3+st)&127;
        }
        float sgn = ((h + k)&1) ? -1.f : 1.f;
        float cf = ctf[o];
        Fc[o] = make_float2((ar0+ar1+ar2+ar3)*sgn*cf, (ai0+ai1+ai2+ai3)*sgn*cf);
    }
}

// Stage D: fft along z (radix-4 x2) + (-1)^{hz+hy+k} + fftshift store.
// grid 512: (ky, class c = kz&3)
__global__ __launch_bounds__(256) void k_volD(const float2* __restrict__ A2,
                       float2* __restrict__ Vr){
    __shared__ float2 sU[32*KX];
    __shared__ float2 sTw[128];
    int tid = threadIdx.x;
    int bid = blockIdx.x;
    int ky = bid >> 2, c = bid & 3;
    make_tw(sTw, tid);
    __syncthreads();
    const float2* base = A2 + (size_t)ky*KX;
    for (int i = tid; i < 32*KX; i += 256){
        int n = i / KX, kk = i - n*KX;
        float2 a  = base[(size_t)(n     )*DD*KX + kk];
        float2 bb = base[(size_t)(n+32)*DD*KX + kk];
        float2 c2 = base[(size_t)(n+64)*DD*KX + kk];
        float2 d  = base[(size_t)(n+96)*DD*KX + kk];
        float acx = a.x + c2.x, acy = a.y + c2.y;
        float amx = a.x - c2.x, amy = a.y - c2.y;
        float bdx = bb.x + d.x, bdy = bb.y + d.y;
        float bmx = bb.x - d.x, bmy = bb.y - d.y;
        float2 u;
        if (c == 0)      u = make_float2(acx + bdx, acy + bdy);
        else if (c == 2) u = make_float2(acx - bdx, acy - bdy);
        else if (c == 1) u = make_float2(amx + bmy, amy - bmx);
        else             u = make_float2(amx - bmy, amy + bmx);
        sU[i] = u;
    }
    __syncthreads();
    float2 w1 = sTw[(8*c)&127];  w1.y = -w1.y;
    float2 w2 = sTw[(16*c)&127]; w2.y = -w2.y;
    float2 w3 = sTw[(24*c)&127]; w3.y = -w3.y;
    for (int i = tid; i < 8*KX; i += 256){
        int n2 = i / KX, kk = i - n2*KX;
        int b0 = n2*KX + kk;
        float2 u0 = sU[b0], u1 = sU[b0+8*KX], u2 = sU[b0+16*KX], u3 = sU[b0+24*KX];
        float2 t1 = cmul(u1,w1), t2 = cmul(u2,w2), t3 = cmul(u3,w3);
        float2 p = make_float2(u0.x+t2.x, u0.y+t2.y);
        float2 q = make_float2(u0.x-t2.x, u0.y-t2.y);
        float2 r = make_float2(t1.x+t3.x, t1.y+t3.y);
        float2 s = make_float2(t1.x-t3.x, t1.y-t3.y);
        sU[b0       ] = make_float2(p.x+r.x, p.y+r.y);
        sU[b0+ 8*KX ] = make_float2(q.x+s.y, q.y-s.x);
        sU[b0+16*KX ] = make_float2(p.x-r.x, p.y-r.y);
        sU[b0+24*KX ] = make_float2(q.x-s.y, q.y+s.x);
    }
    __syncthreads();
    int hy = (ky + 64) & 127;
    for (int o = tid; o < 32*KX; o += 256){
        int m = o / KX, kk = o - m*KX;
        int kz = 4*m + c;
        int hz = (kz + 64) & 127;
        int s4 = m & 3;
        const float2* v = &sU[(8*s4)*KX + kk];
        float ar0=0,ai0=0,ar1=0,ai1=0;
        int j = 0;
        #pragma unroll
        for (int n2 = 0; n2 < 8; n2 += 2){
            float2 v0 = v[n2*KX], v1 = v[(n2+1)*KX];
            float2 e0 = sTw[j]; int jn = (j + kz)&127;
            float2 e1 = sTw[jn];
            ar0 += v0.x*e0.x + v0.y*e0.y;  ai0 += v0.y*e0.x - v0.x*e0.y;
            ar1 += v1.x*e1.x + v1.y*e1.y;  ai1 += v1.y*e1.x - v1.x*e1.y;
            j = (jn + kz)&127;
        }
        float sgn = ((hz + hy + kk) & 1) ? -1.f : 1.f;
        Vr[((size_t)hz*DD + hy)*KX + kk] = make_float2((ar0+ar1)*sgn, (ai0+ai1)*sgn);
    }
}

// Main: per (b,t,g): k in 4 chunks (17,17,17,14); per chunk:
// slice-extract*Fc -> radix-4 level1 -> radix-4 level2 -> 8-term y-IDFT rows
// into disjoint sT columns. Then Hermitian-folded x-irfft (31-dots) -> argmax.
__global__ __launch_bounds__(256,5) void k_main(
    const float2* __restrict__ Vr, const float2* __restrict__ Fc,
    const float* __restrict__ rotm, const float* __restrict__ grid,
    float* __restrict__ resVal, int2* __restrict__ resShift)
{
    __shared__ float2 sP[DD*17];      // 17408 B
    __shared__ float2 sT[WIN*KX];     // 12480 B
    __shared__ float2 sTw[128];       // 1024 B
    __shared__ float  sM[9];

    int tid = threadIdx.x;
    int blk = blockIdx.x;
    int b  = blk / (NTT*NG);
    int rr = blk - b*NTT*NG;
    int t  = rr / NG;
    int g  = rr - t*NG;

    make_tw(sTw, tid);
    if (tid < 9){
        int i = tid/3, k = tid - 3*i;
        const float* R  = rotm + (size_t)(b*NTT + t)*9;
        const float* Gm = grid + (size_t)g*9;
        sM[tid] = R[i*3+0]*Gm[0*3+k] + R[i*3+1]*Gm[1*3+k] + R[i*3+2]*Gm[2*3+k];
    }
    __syncthreads();

    float M00=sM[0], M01=sM[1], M10=sM[3], M11=sM[4], M20=sM[6], M21=sM[7];

    const int KB[4]  = {0,17,34,51};
    const int NKc[4] = {17,17,17,14};
    #pragma unroll
    for (int cc = 0; cc < 4; ++cc){
        const int kbase = KB[cc];
        const int Nk    = NKc[cc];

        // Phase 1: central slice (trilinear, conj-flip), * Fc (= fimg*ctf), conj
        for (int idx = tid; idx < DD*Nk; idx += 256){
            int h = idx / Nk, kk = idx - h*Nk;
            int w = kbase + kk;
            float fy = (h - 64)*(1.0f/128.0f);
            float fx = w*(1.0f/128.0f);
            float rz  = M21*fy + M20*fx;
            float ryv = M11*fy + M10*fx;
            float rx  = M01*fy + M00*fx;
            bool neg = rx < 0.f;
            if (neg){ rz=-rz; ryv=-ryv; rx=-rx; }
            float zi = rz*128.f + 64.f;
            float yi = ryv*128.f + 64.f;
            float xi = rx*128.f;
            float z0f = floorf(zi), y0f = floorf(yi), x0f = floorf(xi);
            float fz2 = zi - z0f, fy2 = yi - y0f, fx2 = xi - x0f;
            int z0 = (int)z0f, y0 = (int)y0f, x0 = (int)x0f;
            float wx0 = (x0 <= 64) ? (1.f - fx2) : 0.f;   // x0 >= 0 always
            float wx1 = (x0 <= 63) ? fx2 : 0.f;
            bool hi = (x0 > 63);
            int xb = hi ? 63 : x0;
            float sr = 0.f, si = 0.f;
            #pragma unroll
            for (int c4 = 0; c4 < 4; ++c4){
                int dz = c4>>1, dy = c4&1;
                int zc = z0+dz, yc = y0+dy;
                float wzy = (dz?fz2:1.f-fz2)*(dy?fy2:1.f-fy2);
                bool okr = (zc>=0) & (zc<DD) & (yc>=0) & (yc<DD);
                wzy = okr ? wzy : 0.f;
                int zcc = min(max(zc,0),DD-1), ycc = min(max(yc,0),DD-1);
                f4 v = *reinterpret_cast<const f4*>(&Vr[((size_t)zcc*DD + ycc)*KX + xb]);
                float c0x = hi ? v.z : v.x;
                float c0y = hi ? v.w : v.y;
                float w0 = wzy*wx0, w1 = wzy*wx1;
                sr += c0x*w0 + v.z*w1;
                si += c0y*w0 + v.w*w1;
            }
            if (neg) si = -si;
            float2 f = Fc[(size_t)(b*DD + h)*KX + w];
            sP[h*17 + kk] = make_float2(f.x*sr + f.y*si, f.y*sr - f.x*si);
        }
        __syncthreads();

        // Level 1 (inverse: u_c = a + i^c b + (-1)^c c2 + (-i)^c d), rows 32c+n
        for (int i = tid; i < 32*Nk; i += 256){
            int n = i / Nk, kk = i - n*Nk;
            int o0 = n*17 + kk;
            float2 a  = sP[o0];
            float2 bb = sP[o0 + 32*17];
            float2 c2 = sP[o0 + 64*17];
            float2 d  = sP[o0 + 96*17];
            float acx = a.x + c2.x, acy = a.y + c2.y;
            float amx = a.x - c2.x, amy = a.y - c2.y;
            float bdx = bb.x + d.x, bdy = bb.y + d.y;
            float bmx = bb.x - d.x, bmy = bb.y - d.y;
            sP[o0        ] = make_float2(acx + bdx, acy + bdy);   // c=0
            sP[o0 + 32*17] = make_float2(amx - bmy, amy + bmx);   // c=1: + i(b-d)
            sP[o0 + 64*17] = make_float2(acx - bdx, acy - bdy);   // c=2
            sP[o0 + 96*17] = make_float2(amx + bmy, amy - bmx);   // c=3: - i(b-d)
        }
        __syncthreads();

        // Level 2 in place (inverse): v_s[n2] = sum_j u[n2+8j] w^{cj} i^{sj},
        // row (32c + 8s + n2); per-thread read set == write set (no race).
        for (int i = tid; i < 32*Nk; i += 256){
            int q = i / Nk, kk = i - q*Nk;
            int c = q >> 3, n2 = q & 7;
            int b0 = (32*c + n2)*17 + kk;
            float2 u0 = sP[b0], u1 = sP[b0+8*17], u2 = sP[b0+16*17], u3 = sP[b0+24*17];
            float2 w1 = sTw[(8*c)&127], w2 = sTw[(16*c)&127], w3 = sTw[(24*c)&127];
            float2 t1 = cmul(u1,w1), t2 = cmul(u2,w2), t3 = cmul(u3,w3);
            float2 p  = make_float2(u0.x+t2.x, u0.y+t2.y);
            float2 qq = make_float2(u0.x-t2.x, u0.y-t2.y);
            float2 r  = make_float2(t1.x+t3.x, t1.y+t3.y);
            float2 s  = make_float2(t1.x-t3.x, t1.y-t3.y);
            sP[b0       ] = make_float2(p.x+r.x,  p.y+r.y);    // s=0
            sP[b0+ 8*17 ] = make_float2(qq.x-s.y, qq.y+s.x);   // s=1: q + i s
            sP[b0+16*17 ] = make_float2(p.x-r.x,  p.y-r.y);    // s=2
            sP[b0+24*17 ] = make_float2(qq.x+s.y, qq.y-s.x);   // s=3: q - i s
        }
        __syncthreads();

        // Phase 2: 8-term y-IDFT per needed row
        for (int o = tid; o < WIN*Nk; o += 256){
            int a = o / Nk, kk = o - a*Nk;
            int ry = (116 + a) & 127;
            int c = ry & 3, s4 = (ry >> 2) & 3;
            const float2* v = &sP[(32*c + 8*s4)*17 + kk];
            float ar0=0,ai0=0,ar1=0,ai1=0;
            int j = 0;
            #pragma unroll
            for (int n2 = 0; n2 < 8; n2 += 2){
                float2 v0 = v[n2*17], v1 = v[(n2+1)*17];
                float2 e0 = sTw[j]; int jn = (j + ry)&127;
                float2 e1 = sTw[jn];
                ar0 += v0.x*e0.x - v0.y*e0.y;  ai0 += v0.x*e0.y + v0.y*e0.x;
                ar1 += v1.x*e1.x - v1.y*e1.y;  ai1 += v1.x*e1.y + v1.y*e1.x;
                j = (jn + ry)&127;
            }
            float sgn = (a & 1) ? -(1.f/128.f) : (1.f/128.f);   // (-1)^ry / 128
            sT[a*KX + kbase + kk] = make_float2((ar0+ar1)*sgn, (ai0+ai1)*sgn);
        }
        __syncthreads();
    }

    // Phase 3a: Hermitian fold. Ae/Ao[a][k-1], k=1..31, in sP (now free).
    // Ae = T[k] + conj(T[64-k]) (even rx), Ao = T[k] - conj(T[64-k]) (odd rx)
    float2* sPf = sP;
    for (int o = tid; o < WIN*31; o += 256){
        int a = o / 31, km1 = o - a*31;
        int k = km1 + 1;
        const float2* Trow = &sT[a*KX];
        float2 T1 = Trow[k], T2 = Trow[64-k];
        sPf[a*31 + km1]       = make_float2(T1.x + T2.x, T1.y - T2.y);
        sPf[744 + a*31 + km1] = make_float2(T1.x - T2.x, T1.y + T2.y);
    }
    __syncthreads();

    // Phase 3b: 31-term folded x-irfft on the 24x24 window
    float* sC = reinterpret_cast<float*>(sP + 1488);
    for (int o = tid; o < WIN*WIN; o += 256){
        int a = o / WIN, bx = o - a*WIN;
        int rx = (116 + bx) & 127;
        const float2* Trow = &sT[a*KX];
        float2 T32 = Trow[32];
        float base = Trow[0].x + ((bx & 1) ? -Trow[64].x : Trow[64].x);
        int r4 = rx & 3;
        base += (r4==0) ?  2.f*T32.x : (r4==1) ? -2.f*T32.y
              : (r4==2) ? -2.f*T32.x :  2.f*T32.y;
        const float2* A = sPf + ((bx & 1) ? 744 : 0) + a*31 - 1;  // A[k], k=1..31
        float acc0=0.f, acc1=0.f;
        int j1 = rx, j2 = (2*rx)&127;
        int st = (2*rx)&127;
        for (int k = 1; k < 31; k += 2){
            float2 e1 = sTw[j1]; float2 A1v = A[k];
            float2 e2 = sTw[j2]; float2 A2v = A[k+1];
            acc0 += A1v.x*e1.x - A1v.y*e1.y;
            acc1 += A2v.x*e2.x - A2v.y*e2.y;
            j1=(j1+st)&127; j2=(j2+st)&127;
        }
        {
            float2 e = sTw[(31*rx)&127]; float2 Av = A[31];
            acc0 += Av.x*e.x - Av.y*e.y;
        }
        sC[o] = (base + 2.f*(acc0+acc1))*(1.f/128.f);
    }
    __syncthreads();

    // Phase 4: argmax, row-major first occurrence tie-break
    float best = -FLT_MAX; int bidx = 0;
    for (int i = tid; i < WIN*WIN; i += 256){
        float v = sC[i];
        if (v > best){ best = v; bidx = i; }
    }
    float* sRv = sC + WIN*WIN;
    int*   sRi = reinterpret_cast<int*>(sRv + 256);
    sRv[tid] = best; sRi[tid] = bidx;
    __syncthreads();
    for (int s = 128; s > 0; s >>= 1){
        if (tid < s){
            float v2 = sRv[tid+s]; int i2 = sRi[tid+s];
            float v1 = sRv[tid];   int i1 = sRi[tid];
            if (v2 > v1 || (v2 == v1 && i2 < i1)){ sRv[tid] = v2; sRi[tid] = i2; }
        }
        __syncthreads();
    }
    if (tid == 0){
        int i = sRi[0];
        int a = i / WIN, bx = i - a*WIN;
        resVal[blk] = sRv[0];
        resShift[blk] = make_int2(H0 + bx, H0 + a);
    }
}

// Final: per-batch top-2 (stable ties), mean/std(ddof=1), erf — parallel.
__global__ __launch_bounds__(256) void k_final(const float* __restrict__ resVal,
                        const int2* __restrict__ resShift,
                        const float* __restrict__ grid, float* __restrict__ out)
{
    __shared__ float sv[256];
    __shared__ int   si[256];
    __shared__ float sr[256];
    __shared__ float sMean;
    const int N = NTT*NG;   // 250
    int b = blockIdx.x, tid = threadIdx.x;
    const float* v = resVal + (size_t)b*N;
    float myv = (tid < N) ? v[tid] : -FLT_MAX;

    sv[tid] = myv; si[tid] = (tid < N) ? tid : 0x7fffffff;
    __syncthreads();
    for (int s = 128; s > 0; s >>= 1){
        if (tid < s){
            float v2 = sv[tid+s]; int i2 = si[tid+s];
            if (v2 > sv[tid] || (v2 == sv[tid] && i2 < si[tid])){ sv[tid]=v2; si[tid]=i2; }
        }
        __syncthreads();
    }
    float v0 = sv[0]; int i0 = si[0];
    __syncthreads();

    bool act = (tid < N) && (tid != i0);
    sv[tid] = act ? myv : -FLT_MAX; si[tid] = act ? tid : 0x7fffffff;
    __syncthreads();
    for (int s = 128; s > 0; s >>= 1){
        if (tid < s){
            float v2 = sv[tid+s]; int i2 = si[tid+s];
            if (v2 > sv[tid] || (v2 == sv[tid] && i2 < si[tid])){ sv[tid]=v2; si[tid]=i2; }
        }
        __syncthreads();
    }
    float v1 = sv[0]; int i1 = si[0];
    __syncthreads();

    sr[tid] = (tid < N) ? myv : 0.f;
    __syncthreads();
    for (int s = 128; s > 0; s >>= 1){
        if (tid < s) sr[tid] += sr[tid+s];
        __syncthreads();
    }
    if (tid == 0) sMean = sr[0] / (float)N;
    __syncthreads();
    float mean = sMean;

    float d = (tid < N) ? (myv - mean) : 0.f;
    sr[tid] = d*d;
    __syncthreads();
    for (int s = 128; s > 0; s >>= 1){
        if (tid < s) sr[tid] += sr[tid+s];
        __syncthreads();
    }

    if (tid == 0){
        float stdv = sqrtf(sr[0] / (float)(N - 1));
        float vals[2] = {v0, v1};
        int   idxs[2] = {i0, i1};
        for (int k = 0; k < 2; ++k){
            out[b*2 + k] = vals[k];
            int gi = idxs[k] % NG;
            for (int j = 0; j < 9; ++j) out[8 + (b*2+k)*9 + j] = grid[(size_t)gi*9 + j];
            int2 sh = resShift[(size_t)b*N + idxs[k]];
            out[80 + (b*2+k)*2 + 0] = -((float)sh.x - 64.f)*1.5f;
            out[80 + (b*2+k)*2 + 1] = -((float)sh.y - 64.f)*1.5f;
            out[96 + b*2 + k] = 0.5f*(1.f + erff((vals[k] - mean)/(stdv*1.41421356237309515f)));
        }
    }
}

extern "C" void kernel_launch(void* const* d_in, const int* in_sizes, int n_in,
                              void* d_out, int out_size, void* d_ws, size_t ws_size,
                              hipStream_t stream)
{
    const float* vol  = (const float*)d_in[0];
    const float* imgs = (const float*)d_in[1];
    const float* ctf  = (const float*)d_in[2];
    const float* rotm = (const float*)d_in[3];
    const float* grid = (const float*)d_in[4];
    float* out = (float*)d_out;

    char* ws = (char*)d_ws;
    size_t off = 0;
    float2* A1 = (float2*)(ws + off); off += (size_t)DD*DD*KX*sizeof(float2);
    float2* A2 = (float2*)(ws + off); off += (size_t)DD*DD*KX*sizeof(float2);
    float2* Vr = (float2*)(ws + off); off += (size_t)DD*DD*KX*sizeof(float2);
    float2* B1 = (float2*)(ws + off); off += (size_t)NB*DD*KX*sizeof(float2);
    float2* Fc = (float2*)(ws + off); off += (size_t)NB*DD*KX*sizeof(float2);
    float* resVal = (float*)(ws + off); off += (size_t)NBTG*sizeof(float);
    int2* resShift = (int2*)(ws + off); off += (size_t)NBTG*sizeof(int2);

    k_stageA<<<642, 256, 0, stream>>>(vol, imgs, A1, B1);
    k_stageB<<<642, 256, 0, stream>>>(A1, ctf, B1, A2, Fc);
    k_volD  <<<512, 256, 0, stream>>>(A2, Vr);
    k_main  <<<NBTG,256, 0, stream>>>(Vr, Fc, rotm, grid, resVal, resShift);
    k_final <<<NB,  256, 0, stream>>>(resVal, resShift, grid, out);
}

// Round 6
// 115.288 us; speedup vs baseline: 6.7606x; 1.1262x over previous
//
#include <hip/hip_runtime.h>
#include <math.h>
#include <float.h>

#define DD   128
#define KX   65          // D/2+1
#define NB   4
#define NTT  2
#define NG   125
#define NBTG (NB*NTT*NG) // 1000
#define WIN  24
#define H0   52

typedef float f4 __attribute__((ext_vector_type(4), aligned(8)));

__device__ __forceinline__ float2 cmul(float2 a, float2 b){
    return make_float2(a.x*b.x - a.y*b.y, a.x*b.y + a.y*b.x);
}

// inline twiddle table: sTw[m] = e^{+2*pi*i*m/128}
__device__ __forceinline__ void make_tw(float2* sTw, int tid){
    if (tid < 128){
        float s, c;
        sincosf((float)tid * (float)(M_PI/64.0), &s, &c);
        sTw[tid] = make_float2(c, s);
    }
}

// Stage A (fused): bid<512 -> vol rfft-x via 2-real-rows-as-complex +
// radix-4 x2 levels + 8-term dots + Hermitian unpack;
// bid>=512 -> image rfft-x (direct).
__global__ __launch_bounds__(256) void k_stageA(const float* __restrict__ vol,
                       const float* __restrict__ imgs,
                       float2* __restrict__ A1, float2* __restrict__ B1){
    __shared__ float2 sZ [16*DD];   // 16 KB
    __shared__ float2 sZ2[16*DD];   // 16 KB
    __shared__ float2 sTw[128];
    int tid = threadIdx.x;
    int bid = blockIdx.x;
    make_tw(sTw, tid);
    __syncthreads();

    if (bid < 512){
        int z = bid >> 2, q = bid & 3;
        int y0 = q*32;
        float fz = (z-64)*(1.0f/128.0f);
        // load 16 row-pairs as complex, sinc^2 weighted
        for (int i = tid; i < 16*DD; i += 256){
            int p = i >> 7, x = i & 127;
            int yA = y0 + 2*p;
            float fx = (x-64)*(1.0f/128.0f);
            float fyA = (yA-64)*(1.0f/128.0f);
            float fyB = fyA + (1.0f/128.0f);
            float b2 = fz*fz + fx*fx;
            float rA = sqrtf(b2 + fyA*fyA);
            float rB = sqrtf(b2 + fyB*fyB);
            float sA = (rA > 0.f) ? (sinf((float)M_PI*rA)/((float)M_PI*rA)) : 1.f;
            float sB = (rB > 0.f) ? (sinf((float)M_PI*rB)/((float)M_PI*rB)) : 1.f;
            float a = vol[(z*DD + yA)*DD + x] * sA * sA;
            float b = vol[(z*DD + yA+1)*DD + x] * sB * sB;
            sZ[i] = make_float2(a, b);
        }
        __syncthreads();
        // level 1 (forward): u_c[x1] = sum_j z[x1+32j] (-i)^{cj}, at p*DD+32c+x1
        for (int i = tid; i < 16*32; i += 256){
            int p = i >> 5, x1 = i & 31;
            int b0 = p*DD + x1;
            float2 a = sZ[b0], bb = sZ[b0+32], c2 = sZ[b0+64], d = sZ[b0+96];
            float acx=a.x+c2.x, acy=a.y+c2.y;
            float amx=a.x-c2.x, amy=a.y-c2.y;
            float bdx=bb.x+d.x, bdy=bb.y+d.y;
            float bmx=bb.x-d.x, bmy=bb.y-d.y;
            sZ[b0   ] = make_float2(acx+bdx, acy+bdy);     // c=0
            sZ[b0+32] = make_float2(amx+bmy, amy-bmx);     // c=1: (a-c2)-i(b-d)
            sZ[b0+64] = make_float2(acx-bdx, acy-bdy);     // c=2
            sZ[b0+96] = make_float2(amx-bmy, amy+bmx);     // c=3: +i(b-d)
        }
        __syncthreads();
        // level 2 (forward, in place): v_{c,s}[x2] = sum_j u_c[x2+8j] conj(w)^{cj} (-i)^{sj}
        for (int i = tid; i < 16*32; i += 256){
            int p = i >> 5, r5 = i & 31;
            int c = r5 >> 3, x2 = r5 & 7;
            int b0 = p*DD + 32*c + x2;
            float2 u0 = sZ[b0], u1 = sZ[b0+8], u2 = sZ[b0+16], u3 = sZ[b0+24];
            float2 w1 = sTw[(8*c)&127];  w1.y = -w1.y;
            float2 w2 = sTw[(16*c)&127]; w2.y = -w2.y;
            float2 w3 = sTw[(24*c)&127]; w3.y = -w3.y;
            float2 t1 = cmul(u1,w1), t2 = cmul(u2,w2), t3 = cmul(u3,w3);
            float2 pp = make_float2(u0.x+t2.x, u0.y+t2.y);
            float2 qq = make_float2(u0.x-t2.x, u0.y-t2.y);
            float2 rr = make_float2(t1.x+t3.x, t1.y+t3.y);
            float2 ss = make_float2(t1.x-t3.x, t1.y-t3.y);
            sZ[b0   ] = make_float2(pp.x+rr.x, pp.y+rr.y);   // s=0
            sZ[b0+8 ] = make_float2(qq.x+ss.y, qq.y-ss.x);   // s=1: q - i s
            sZ[b0+16] = make_float2(pp.x-rr.x, pp.y-rr.y);   // s=2
            sZ[b0+24] = make_float2(qq.x-ss.y, qq.y+ss.x);   // s=3: q + i s
        }
        __syncthreads();
        // 8-term dots: Z[k] = sum_{x2} v_{c,s}[x2] conj(sTw[k*x2])
        for (int i = tid; i < 16*DD; i += 256){
            int p = i >> 7, k = i & 127;
            int c = k & 3, s = (k >> 2) & 3;
            const float2* v = &sZ[p*DD + 32*c + 8*s];
            float ar0=0,ai0=0,ar1=0,ai1=0;
            int j = 0;
            #pragma unroll
            for (int x2 = 0; x2 < 8; x2 += 2){
                float2 v0 = v[x2], v1 = v[x2+1];
                float2 e0 = sTw[j]; int jn = (j + k)&127;
                float2 e1 = sTw[jn];
                ar0 += v0.x*e0.x + v0.y*e0.y;  ai0 += v0.y*e0.x - v0.x*e0.y;
                ar1 += v1.x*e1.x + v1.y*e1.y;  ai1 += v1.y*e1.x - v1.x*e1.y;
                j = (jn + k)&127;
            }
            sZ2[i] = make_float2(ar0+ar1, ai0+ai1);
        }
        __syncthreads();
        // unpack: A = (Z[k]+conj(Z[-k]))/2, B = (Z[k]-conj(Z[-k]))/(2i)
        for (int i = tid; i < 16*KX; i += 256){
            int p = i / KX, k = i - p*KX;
            float2 Zk = sZ2[p*DD + k];
            float2 Zm = sZ2[p*DD + ((128-k)&127)];
            float2 A = make_float2(0.5f*(Zk.x+Zm.x), 0.5f*(Zk.y-Zm.y));
            float Dx = Zk.x - Zm.x, Dy = Zk.y + Zm.y;
            float2 Bv = make_float2(0.5f*Dy, -0.5f*Dx);
            int yA = y0 + 2*p;
            A1[(z*DD + yA  )*KX + k] = A;
            A1[(z*DD + yA+1)*KX + k] = Bv;
        }
    } else {
        int o = (bid - 512)*256 + tid;
        if (o >= NB*DD*KX) return;
        int b = o / (DD*KX);
        int r = o - b*DD*KX;
        int y = r / KX, k = r - y*KX;
        const float* row = imgs + (b*DD + y)*DD;
        float ar0=0,ai0=0,ar1=0,ai1=0,ar2=0,ai2=0,ar3=0,ai3=0;
        int i0=0, i1=k&127, i2=(2*k)&127, i3=(3*k)&127;
        int st = (4*k)&127;
        for (int x = 0; x < DD; x += 4){
            float v0=row[x], v1=row[x+1], v2=row[x+2], v3=row[x+3];
            float2 e0=sTw[i0], e1=sTw[i1], e2=sTw[i2], e3=sTw[i3];
            ar0 += v0*e0.x; ai0 -= v0*e0.y;
            ar1 += v1*e1.x; ai1 -= v1*e1.y;
            ar2 += v2*e2.x; ai2 -= v2*e2.y;
            ar3 += v3*e3.x; ai3 -= v3*e3.y;
            i0=(i0+st)&127; i1=(i1+st)&127; i2=(i2+st)&127; i3=(i3+st)&127;
        }
        B1[o] = make_float2(ar0+ar1+ar2+ar3, ai0+ai1+ai2+ai3);
    }
}

// Stage B (fused): bid<512 -> vol fft-y radix-4 x2 levels (class per block);
//                  bid>=512 -> image fft-y + signs + ctf premul -> Fc.
__global__ __launch_bounds__(256) void k_stageB(const float2* __restrict__ A1,
                       const float* __restrict__ ctf, const float2* __restrict__ B1,
                       float2* __restrict__ A2, float2* __restrict__ Fc){
    __shared__ float2 sU[32*KX];   // 16640 B
    __shared__ float2 sTw[128];
    int tid = threadIdx.x;
    int bid = blockIdx.x;
    make_tw(sTw, tid);
    __syncthreads();

    if (bid < 512){
        int z = bid >> 2, c = bid & 3;
        const float2* base = A1 + z*DD*KX;
        for (int i = tid; i < 32*KX; i += 256){
            int n = i / KX, kk = i - n*KX;
            float2 a  = base[(n    )*KX + kk];
            float2 bb = base[(n+32)*KX + kk];
            float2 c2 = base[(n+64)*KX + kk];
            float2 d  = base[(n+96)*KX + kk];
            float acx = a.x + c2.x, acy = a.y + c2.y;
            float amx = a.x - c2.x, amy = a.y - c2.y;
            float bdx = bb.x + d.x, bdy = bb.y + d.y;
            float bmx = bb.x - d.x, bmy = bb.y - d.y;
            float2 u;
            if (c == 0)      u = make_float2(acx + bdx, acy + bdy);
            else if (c == 2) u = make_float2(acx - bdx, acy - bdy);
            else if (c == 1) u = make_float2(amx + bmy, amy - bmx);   // (a-c2) - i(b-d)
            else             u = make_float2(amx - bmy, amy + bmx);   // (a-c2) + i(b-d)
            sU[i] = u;
        }
        __syncthreads();
        float2 w1 = sTw[(8*c)&127];  w1.y = -w1.y;
        float2 w2 = sTw[(16*c)&127]; w2.y = -w2.y;
        float2 w3 = sTw[(24*c)&127]; w3.y = -w3.y;
        for (int i = tid; i < 8*KX; i += 256){
            int n2 = i / KX, kk = i - n2*KX;
            int b0 = n2*KX + kk;
            float2 u0 = sU[b0], u1 = sU[b0+8*KX], u2 = sU[b0+16*KX], u3 = sU[b0+24*KX];
            float2 t1 = cmul(u1,w1), t2 = cmul(u2,w2), t3 = cmul(u3,w3);
            float2 p = make_float2(u0.x+t2.x, u0.y+t2.y);
            float2 q = make_float2(u0.x-t2.x, u0.y-t2.y);
            float2 r = make_float2(t1.x+t3.x, t1.y+t3.y);
            float2 s = make_float2(t1.x-t3.x, t1.y-t3.y);
            sU[b0       ] = make_float2(p.x+r.x, p.y+r.y);   // s=0
            sU[b0+ 8*KX ] = make_float2(q.x+s.y, q.y-s.x);   // s=1: q - i s
            sU[b0+16*KX ] = make_float2(p.x-r.x, p.y-r.y);   // s=2
            sU[b0+24*KX ] = make_float2(q.x-s.y, q.y+s.x);   // s=3: q + i s
        }
        __syncthreads();
        for (int o = tid; o < 32*KX; o += 256){
            int m = o / KX, kk = o - m*KX;
            int ky = 4*m + c;
            int s4 = m & 3;
            const float2* v = &sU[(8*s4)*KX + kk];
            float ar0=0,ai0=0,ar1=0,ai1=0;
            int j = 0;
            #pragma unroll
            for (int n2 = 0; n2 < 8; n2 += 2){
                float2 v0 = v[n2*KX], v1 = v[(n2+1)*KX];
                float2 e0 = sTw[j]; int jn = (j + ky)&127;
                float2 e1 = sTw[jn];
                ar0 += v0.x*e0.x + v0.y*e0.y;  ai0 += v0.y*e0.x - v0.x*e0.y;
                ar1 += v1.x*e1.x + v1.y*e1.y;  ai1 += v1.y*e1.x - v1.x*e1.y;
                j = (jn + ky)&127;
            }
            A2[(z*DD + ky)*KX + kk] = make_float2(ar0+ar1, ai0+ai1);
        }
    } else {
        int o = (bid - 512)*256 + tid;
        if (o >= NB*DD*KX) return;
        int b = o / (DD*KX);
        int r = o - b*DD*KX;
        int h = r / KX, k = r - h*KX;
        int kky = (h + 64) & 127;
        const float2* col = B1 + b*DD*KX + k;
        float ar0=0,ai0=0,ar1=0,ai1=0,ar2=0,ai2=0,ar3=0,ai3=0;
        int i0=0, i1=kky&127, i2=(2*kky)&127, i3=(3*kky)&127;
        int st = (4*kky)&127;
        for (int y = 0; y < DD; y += 4){
            float2 v0=col[(y+0)*KX], v1=col[(y+1)*KX];
            float2 v2=col[(y+2)*KX], v3=col[(y+3)*KX];
            float2 e0=sTw[i0], e1=sTw[i1], e2=sTw[i2], e3=sTw[i3];
            ar0 += v0.x*e0.x + v0.y*e0.y;  ai0 += v0.y*e0.x - v0.x*e0.y;
            ar1 += v1.x*e1.x + v1.y*e1.y;  ai1 += v1.y*e1.x - v1.x*e1.y;
            ar2 += v2.x*e2.x + v2.y*e2.y;  ai2 += v2.y*e2.x - v2.x*e2.y;
            ar3 += v3.x*e3.x + v3.y*e3.y;  ai3 += v3.y*e3.x - v3.x*e3.y;
            i0=(i0+st)&127; i1=(i1+st)&127; i2=(i2+st)&127; i3=(i3+st)&127;
        }
        float sgn = ((h + k)&1) ? -1.f : 1.f;
        float cf = ctf[o];
        Fc[o] = make_float2((ar0+ar1+ar2+ar3)*sgn*cf, (ai0+ai1+ai2+ai3)*sgn*cf);
    }
}

// Stage D: fft along z (radix-4 x2) + (-1)^{hz+hy+k} + fftshift store.
__global__ __launch_bounds__(256) void k_volD(const float2* __restrict__ A2,
                       float2* __restrict__ Vr){
    __shared__ float2 sU[32*KX];
    __shared__ float2 sTw[128];
    int tid = threadIdx.x;
    int bid = blockIdx.x;
    int ky = bid >> 2, c = bid & 3;
    make_tw(sTw, tid);
    __syncthreads();
    const float2* base = A2 + ky*KX;
    for (int i = tid; i < 32*KX; i += 256){
        int n = i / KX, kk = i - n*KX;
        float2 a  = base[(n    )*DD*KX + kk];
        float2 bb = base[(n+32)*DD*KX + kk];
        float2 c2 = base[(n+64)*DD*KX + kk];
        float2 d  = base[(n+96)*DD*KX + kk];
        float acx = a.x + c2.x, acy = a.y + c2.y;
        float amx = a.x - c2.x, amy = a.y - c2.y;
        float bdx = bb.x + d.x, bdy = bb.y + d.y;
        float bmx = bb.x - d.x, bmy = bb.y - d.y;
        float2 u;
        if (c == 0)      u = make_float2(acx + bdx, acy + bdy);
        else if (c == 2) u = make_float2(acx - bdx, acy - bdy);
        else if (c == 1) u = make_float2(amx + bmy, amy - bmx);
        else             u = make_float2(amx - bmy, amy + bmx);
        sU[i] = u;
    }
    __syncthreads();
    float2 w1 = sTw[(8*c)&127];  w1.y = -w1.y;
    float2 w2 = sTw[(16*c)&127]; w2.y = -w2.y;
    float2 w3 = sTw[(24*c)&127]; w3.y = -w3.y;
    for (int i = tid; i < 8*KX; i += 256){
        int n2 = i / KX, kk = i - n2*KX;
        int b0 = n2*KX + kk;
        float2 u0 = sU[b0], u1 = sU[b0+8*KX], u2 = sU[b0+16*KX], u3 = sU[b0+24*KX];
        float2 t1 = cmul(u1,w1), t2 = cmul(u2,w2), t3 = cmul(u3,w3);
        float2 p = make_float2(u0.x+t2.x, u0.y+t2.y);
        float2 q = make_float2(u0.x-t2.x, u0.y-t2.y);
        float2 r = make_float2(t1.x+t3.x, t1.y+t3.y);
        float2 s = make_float2(t1.x-t3.x, t1.y-t3.y);
        sU[b0       ] = make_float2(p.x+r.x, p.y+r.y);
        sU[b0+ 8*KX ] = make_float2(q.x+s.y, q.y-s.x);
        sU[b0+16*KX ] = make_float2(p.x-r.x, p.y-r.y);
        sU[b0+24*KX ] = make_float2(q.x-s.y, q.y+s.x);
    }
    __syncthreads();
    int hy = (ky + 64) & 127;
    for (int o = tid; o < 32*KX; o += 256){
        int m = o / KX, kk = o - m*KX;
        int kz = 4*m + c;
        int hz = (kz + 64) & 127;
        int s4 = m & 3;
        const float2* v = &sU[(8*s4)*KX + kk];
        float ar0=0,ai0=0,ar1=0,ai1=0;
        int j = 0;
        #pragma unroll
        for (int n2 = 0; n2 < 8; n2 += 2){
            float2 v0 = v[n2*KX], v1 = v[(n2+1)*KX];
            float2 e0 = sTw[j]; int jn = (j + kz)&127;
            float2 e1 = sTw[jn];
            ar0 += v0.x*e0.x + v0.y*e0.y;  ai0 += v0.y*e0.x - v0.x*e0.y;
            ar1 += v1.x*e1.x + v1.y*e1.y;  ai1 += v1.y*e1.x - v1.x*e1.y;
            j = (jn + kz)&127;
        }
        float sgn = ((hz + hy + kk) & 1) ? -1.f : 1.f;
        Vr[(hz*DD + hy)*KX + kk] = make_float2((ar0+ar1)*sgn, (ai0+ai1)*sgn);
    }
}

// Main: per (b,t,g): k in 4 chunks (17,17,17,14); per chunk:
// slice-extract*Fc -> radix-4 level1 -> level2 -> 8-term y-IDFT rows
// into disjoint sT columns. Then Hermitian-folded x-irfft -> wave argmax.
__global__ __launch_bounds__(256,4) void k_main(
    const float2* __restrict__ Vr, const float2* __restrict__ Fc,
    const float* __restrict__ rotm, const float* __restrict__ grid,
    float* __restrict__ resVal, int2* __restrict__ resShift)
{
    __shared__ float2 sP[DD*17];      // 17408 B
    __shared__ float2 sT[WIN*KX];     // 12480 B
    __shared__ float2 sTw[128];       // 1024 B
    __shared__ float  sM[9];
    __shared__ float  swv[4];
    __shared__ int    swi[4];

    int tid = threadIdx.x;
    int blk = blockIdx.x;
    int b  = blk / (NTT*NG);
    int rr = blk - b*NTT*NG;
    int t  = rr / NG;
    int g  = rr - t*NG;

    make_tw(sTw, tid);
    if (tid < 9){
        int i = tid/3, k = tid - 3*i;
        const float* R  = rotm + (b*NTT + t)*9;
        const float* Gm = grid + g*9;
        sM[tid] = R[i*3+0]*Gm[0*3+k] + R[i*3+1]*Gm[1*3+k] + R[i*3+2]*Gm[2*3+k];
    }
    __syncthreads();

    float M00=sM[0], M01=sM[1], M10=sM[3], M11=sM[4], M20=sM[6], M21=sM[7];
    const float2* FcB = Fc + b*DD*KX;

    const int KB[4]  = {0,17,34,51};
    const int NKc[4] = {17,17,17,14};
    #pragma unroll
    for (int cc = 0; cc < 4; ++cc){
        const int kbase = KB[cc];
        const int Nk    = NKc[cc];

        // Phase 1: central slice (trilinear, conj-flip), * Fc (= fimg*ctf), conj
        #pragma unroll 2
        for (int idx = tid; idx < DD*Nk; idx += 256){
            int h = idx / Nk, kk = idx - h*Nk;
            int w = kbase + kk;
            float hf = (float)(h - 64);
            float wf = (float)w;
            float xi = M01*hf + M00*wf;           // rx*128
            float zi = M21*hf + M20*wf + 64.f;
            float yi = M11*hf + M10*wf + 64.f;
            bool neg = xi < 0.f;
            if (neg){ xi = -xi; zi = 128.f - zi; yi = 128.f - yi; }
            float z0f = floorf(zi), y0f = floorf(yi), x0f = floorf(xi);
            float fz2 = zi - z0f, fy2 = yi - y0f, fx2 = xi - x0f;
            int z0 = (int)z0f, y0 = (int)y0f, x0 = (int)x0f;
            float wx0 = (x0 <= 64) ? (1.f - fx2) : 0.f;   // x0 >= 0 always
            float wx1 = (x0 <= 63) ? fx2 : 0.f;
            bool hi = (x0 > 63);
            int xb = hi ? 63 : x0;
            float2 f = FcB[h*KX + w];
            float sr = 0.f, si = 0.f;
            #pragma unroll
            for (int c4 = 0; c4 < 4; ++c4){
                int dz = c4>>1, dy = c4&1;
                int zc = z0+dz, yc = y0+dy;
                float wzy = (dz?fz2:1.f-fz2)*(dy?fy2:1.f-fy2);
                bool okr = (zc>=0) & (zc<DD) & (yc>=0) & (yc<DD);
                wzy = okr ? wzy : 0.f;
                int zcc = min(max(zc,0),DD-1), ycc = min(max(yc,0),DD-1);
                int off = (zcc*DD + ycc)*KX + xb;
                f4 v = *reinterpret_cast<const f4*>(Vr + off);
                float c0x = hi ? v.z : v.x;
                float c0y = hi ? v.w : v.y;
                float w0 = wzy*wx0, w1 = wzy*wx1;
                sr += c0x*w0 + v.z*w1;
                si += c0y*w0 + v.w*w1;
            }
            if (neg) si = -si;
            sP[h*17 + kk] = make_float2(f.x*sr + f.y*si, f.y*sr - f.x*si);
        }
        __syncthreads();

        // Level 1 (inverse: u_c = a + i^c b + (-1)^c c2 + (-i)^c d), rows 32c+n
        for (int i = tid; i < 32*Nk; i += 256){
            int n = i / Nk, kk = i - n*Nk;
            int o0 = n*17 + kk;
            float2 a  = sP[o0];
            float2 bb = sP[o0 + 32*17];
            float2 c2 = sP[o0 + 64*17];
            float2 d  = sP[o0 + 96*17];
            float acx = a.x + c2.x, acy = a.y + c2.y;
            float amx = a.x - c2.x, amy = a.y - c2.y;
            float bdx = bb.x + d.x, bdy = bb.y + d.y;
            float bmx = bb.x - d.x, bmy = bb.y - d.y;
            sP[o0        ] = make_float2(acx + bdx, acy + bdy);   // c=0
            sP[o0 + 32*17] = make_float2(amx - bmy, amy + bmx);   // c=1: + i(b-d)
            sP[o0 + 64*17] = make_float2(acx - bdx, acy - bdy);   // c=2
            sP[o0 + 96*17] = make_float2(amx + bmy, amy - bmx);   // c=3: - i(b-d)
        }
        __syncthreads();

        // Level 2 in place (inverse): v_s[n2] = sum_j u[n2+8j] w^{cj} i^{sj}
        for (int i = tid; i < 32*Nk; i += 256){
            int q = i / Nk, kk = i - q*Nk;
            int c = q >> 3, n2 = q & 7;
            int b0 = (32*c + n2)*17 + kk;
            float2 u0 = sP[b0], u1 = sP[b0+8*17], u2 = sP[b0+16*17], u3 = sP[b0+24*17];
            float2 w1 = sTw[(8*c)&127], w2 = sTw[(16*c)&127], w3 = sTw[(24*c)&127];
            float2 t1 = cmul(u1,w1), t2 = cmul(u2,w2), t3 = cmul(u3,w3);
            float2 p  = make_float2(u0.x+t2.x, u0.y+t2.y);
            float2 qq = make_float2(u0.x-t2.x, u0.y-t2.y);
            float2 r  = make_float2(t1.x+t3.x, t1.y+t3.y);
            float2 s  = make_float2(t1.x-t3.x, t1.y-t3.y);
            sP[b0       ] = make_float2(p.x+r.x,  p.y+r.y);    // s=0
            sP[b0+ 8*17 ] = make_float2(qq.x-s.y, qq.y+s.x);   // s=1: q + i s
            sP[b0+16*17 ] = make_float2(p.x-r.x,  p.y-r.y);    // s=2
            sP[b0+24*17 ] = make_float2(qq.x+s.y, qq.y-s.x);   // s=3: q - i s
        }
        __syncthreads();

        // Phase 2: 8-term y-IDFT per needed row
        for (int o = tid; o < WIN*Nk; o += 256){
            int a = o / Nk, kk = o - a*Nk;
            int ry = (116 + a) & 127;
            int c = ry & 3, s4 = (ry >> 2) & 3;
            const float2* v = &sP[(32*c + 8*s4)*17 + kk];
            float ar0=0,ai0=0,ar1=0,ai1=0;
            int j = 0;
            #pragma unroll
            for (int n2 = 0; n2 < 8; n2 += 2){
                float2 v0 = v[n2*17], v1 = v[(n2+1)*17];
                float2 e0 = sTw[j]; int jn = (j + ry)&127;
                float2 e1 = sTw[jn];
                ar0 += v0.x*e0.x - v0.y*e0.y;  ai0 += v0.x*e0.y + v0.y*e0.x;
                ar1 += v1.x*e1.x - v1.y*e1.y;  ai1 += v1.x*e1.y + v1.y*e1.x;
                j = (jn + ry)&127;
            }
            float sgn = (a & 1) ? -(1.f/128.f) : (1.f/128.f);   // (-1)^ry / 128
            sT[a*KX + kbase + kk] = make_float2((ar0+ar1)*sgn, (ai0+ai1)*sgn);
        }
        __syncthreads();
    }

    // Phase 3a: Hermitian fold into sP (free): Ae (even rx) / Ao (odd rx)
    float2* sPf = sP;
    for (int o = tid; o < WIN*31; o += 256){
        int a = o / 31, km1 = o - a*31;
        int k = km1 + 1;
        const float2* Trow = &sT[a*KX];
        float2 T1 = Trow[k], T2 = Trow[64-k];
        sPf[a*31 + km1]       = make_float2(T1.x + T2.x, T1.y - T2.y);
        sPf[744 + a*31 + km1] = make_float2(T1.x - T2.x, T1.y + T2.y);
    }
    __syncthreads();

    // Phase 3b: 31-term folded x-irfft on the 24x24 window
    float* sC = reinterpret_cast<float*>(sP + 1488);
    for (int o = tid; o < WIN*WIN; o += 256){
        int a = o / WIN, bx = o - a*WIN;
        int rx = (116 + bx) & 127;
        const float2* Trow = &sT[a*KX];
        float2 T32 = Trow[32];
        float base = Trow[0].x + ((bx & 1) ? -Trow[64].x : Trow[64].x);
        int r4 = rx & 3;
        base += (r4==0) ?  2.f*T32.x : (r4==1) ? -2.f*T32.y
              : (r4==2) ? -2.f*T32.x :  2.f*T32.y;
        const float2* A = sPf + ((bx & 1) ? 744 : 0) + a*31 - 1;  // A[k], k=1..31
        float acc0=0.f, acc1=0.f;
        int j1 = rx, j2 = (2*rx)&127;
        int st = (2*rx)&127;
        for (int k = 1; k < 31; k += 2){
            float2 e1 = sTw[j1]; float2 A1v = A[k];
            float2 e2 = sTw[j2]; float2 A2v = A[k+1];
            acc0 += A1v.x*e1.x - A1v.y*e1.y;
            acc1 += A2v.x*e2.x - A2v.y*e2.y;
            j1=(j1+st)&127; j2=(j2+st)&127;
        }
        {
            float2 e = sTw[(31*rx)&127]; float2 Av = A[31];
            acc0 += Av.x*e.x - Av.y*e.y;
        }
        sC[o] = (base + 2.f*(acc0+acc1))*(1.f/128.f);
    }
    __syncthreads();

    // Phase 4: argmax, row-major first occurrence — wave-level shfl_xor reduce
    float best = -FLT_MAX; int bidx = 0x7fffffff;
    for (int i = tid; i < WIN*WIN; i += 256){
        float v = sC[i];
        if (v > best){ best = v; bidx = i; }
    }
    #pragma unroll
    for (int s = 32; s > 0; s >>= 1){
        float ov = __shfl_xor(best, s, 64);
        int   oi = __shfl_xor(bidx, s, 64);
        if (ov > best || (ov == best && oi < bidx)){ best = ov; bidx = oi; }
    }
    if ((tid & 63) == 0){ swv[tid>>6] = best; swi[tid>>6] = bidx; }
    __syncthreads();
    if (tid == 0){
        float bv = swv[0]; int bi = swi[0];
        #pragma unroll
        for (int w2 = 1; w2 < 4; ++w2){
            if (swv[w2] > bv || (swv[w2] == bv && swi[w2] < bi)){ bv = swv[w2]; bi = swi[w2]; }
        }
        int a = bi / WIN, bx = bi - a*WIN;
        resVal[blk] = bv;
        resShift[blk] = make_int2(H0 + bx, H0 + a);
    }
}

// Final: per-batch top-2 (stable ties), mean/std(ddof=1), erf — parallel.
__global__ __launch_bounds__(256) void k_final(const float* __restrict__ resVal,
                        const int2* __restrict__ resShift,
                        const float* __restrict__ grid, float* __restrict__ out)
{
    __shared__ float sv[256];
    __shared__ int   si[256];
    __shared__ float sr[256];
    __shared__ float sMean;
    const int N = NTT*NG;   // 250
    int b = blockIdx.x, tid = threadIdx.x;
    const float* v = resVal + b*N;
    float myv = (tid < N) ? v[tid] : -FLT_MAX;

    sv[tid] = myv; si[tid] = (tid < N) ? tid : 0x7fffffff;
    __syncthreads();
    for (int s = 128; s > 0; s >>= 1){
        if (tid < s){
            float v2 = sv[tid+s]; int i2 = si[tid+s];
            if (v2 > sv[tid] || (v2 == sv[tid] && i2 < si[tid])){ sv[tid]=v2; si[tid]=i2; }
        }
        __syncthreads();
    }
    float v0 = sv[0]; int i0 = si[0];
    __syncthreads();

    bool act = (tid < N) && (tid != i0);
    sv[tid] = act ? myv : -FLT_MAX; si[tid] = act ? tid : 0x7fffffff;
    __syncthreads();
    for (int s = 128; s > 0; s >>= 1){
        if (tid < s){
            float v2 = sv[tid+s]; int i2 = si[tid+s];
            if (v2 > sv[tid] || (v2 == sv[tid] && i2 < si[tid])){ sv[tid]=v2; si[tid]=i2; }
        }
        __syncthreads();
    }
    float v1 = sv[0]; int i1 = si[0];
    __syncthreads();

    sr[tid] = (tid < N) ? myv : 0.f;
    __syncthreads();
    for (int s = 128; s > 0; s >>= 1){
        if (tid < s) sr[tid] += sr[tid+s];
        __syncthreads();
    }
    if (tid == 0) sMean = sr[0] / (float)N;
    __syncthreads();
    float mean = sMean;

    float d = (tid < N) ? (myv - mean) : 0.f;
    sr[tid] = d*d;
    __syncthreads();
    for (int s = 128; s > 0; s >>= 1){
        if (tid < s) sr[tid] += sr[tid+s];
        __syncthreads();
    }

    if (tid == 0){
        float stdv = sqrtf(sr[0] / (float)(N - 1));
        float vals[2] = {v0, v1};
        int   idxs[2] = {i0, i1};
        for (int k = 0; k < 2; ++k){
            out[b*2 + k] = vals[k];
            int gi = idxs[k] % NG;
            for (int j = 0; j < 9; ++j) out[8 + (b*2+k)*9 + j] = grid[gi*9 + j];
            int2 sh = resShift[b*N + idxs[k]];
            out[80 + (b*2+k)*2 + 0] = -((float)sh.x - 64.f)*1.5f;
            out[80 + (b*2+k)*2 + 1] = -((float)sh.y - 64.f)*1.5f;
            out[96 + b*2 + k] = 0.5f*(1.f + erff((vals[k] - mean)/(stdv*1.41421356237309515f)));
        }
    }
}

extern "C" void kernel_launch(void* const* d_in, const int* in_sizes, int n_in,
                              void* d_out, int out_size, void* d_ws, size_t ws_size,
                              hipStream_t stream)
{
    const float* vol  = (const float*)d_in[0];
    const float* imgs = (const float*)d_in[1];
    const float* ctf  = (const float*)d_in[2];
    const float* rotm = (const float*)d_in[3];
    const float* grid = (const float*)d_in[4];
    float* out = (float*)d_out;

    char* ws = (char*)d_ws;
    size_t off = 0;
    float2* A1 = (float2*)(ws + off); off += (size_t)DD*DD*KX*sizeof(float2);
    float2* A2 = (float2*)(ws + off); off += (size_t)DD*DD*KX*sizeof(float2);
    float2* Vr = (float2*)(ws + off); off += (size_t)DD*DD*KX*sizeof(float2);
    float2* B1 = (float2*)(ws + off); off += (size_t)NB*DD*KX*sizeof(float2);
    float2* Fc = (float2*)(ws + off); off += (size_t)NB*DD*KX*sizeof(float2);
    float* resVal = (float*)(ws + off); off += (size_t)NBTG*sizeof(float);
    int2* resShift = (int2*)(ws + off); off += (size_t)NBTG*sizeof(int2);

    k_stageA<<<642, 256, 0, stream>>>(vol, imgs, A1, B1);
    k_stageB<<<642, 256, 0, stream>>>(A1, ctf, B1, A2, Fc);
    k_volD  <<<512, 256, 0, stream>>>(A2, Vr);
    k_main  <<<NBTG,256, 0, stream>>>(Vr, Fc, rotm, grid, resVal, resShift);
    k_final <<<NB,  256, 0, stream>>>(resVal, resShift, grid, out);
}